// Round 11
// baseline (2135.813 us; speedup 1.0000x reference)
//
#include <hip/hip_runtime.h>
#include <hip/hip_fp16.h>
#include <cstddef>
#include <cstdint>

namespace {

constexpr int NPROT = 100000;
constexpr int EPROT = 1600000;
constexpr int NLIG  = 5000;
constexpr int ELIG  = 80000;

// ---------------- CSR construction ----------------

__global__ void hist_kernel(const int* __restrict__ dst, int* __restrict__ cnt, int e) {
  int i = blockIdx.x * 256 + threadIdx.x;
  if (i < e) atomicAdd(&cnt[dst[i]], 1);
}

// per-block (1024 elems) exclusive scan; also computes nrm = max(deg,1)^-0.5
__global__ void scan1_kernel(const int* __restrict__ cnt, int* __restrict__ rp,
                             int* __restrict__ bsum, float* __restrict__ nrm, int n) {
  __shared__ int wsum[4];
  int t = threadIdx.x;
  int base = blockIdx.x * 1024 + t * 4;
  int v0 = 0, v1 = 0, v2 = 0, v3 = 0;
  if (base + 3 < n) {
    int4 val = *(const int4*)(cnt + base);
    v0 = val.x; v1 = val.y; v2 = val.z; v3 = val.w;
  } else if (base < n) {
    v0 = cnt[base];
    if (base + 1 < n) v1 = cnt[base + 1];
    if (base + 2 < n) v2 = cnt[base + 2];
  }
  if (base < n)     nrm[base]     = 1.0f / sqrtf(fmaxf((float)v0, 1.0f));
  if (base + 1 < n) nrm[base + 1] = 1.0f / sqrtf(fmaxf((float)v1, 1.0f));
  if (base + 2 < n) nrm[base + 2] = 1.0f / sqrtf(fmaxf((float)v2, 1.0f));
  if (base + 3 < n) nrm[base + 3] = 1.0f / sqrtf(fmaxf((float)v3, 1.0f));
  int ts = v0 + v1 + v2 + v3;
  int lane = t & 63, wv = t >> 6;
  int incl = ts;
  #pragma unroll
  for (int off = 1; off < 64; off <<= 1) {
    int o = __shfl_up(incl, off, 64);
    if (lane >= off) incl += o;
  }
  if (lane == 63) wsum[wv] = incl;
  __syncthreads();
  int woff = 0;
  #pragma unroll
  for (int i = 0; i < 4; ++i) if (i < wv) woff += wsum[i];
  int excl = woff + incl - ts;
  int o0 = excl, o1 = o0 + v0, o2 = o1 + v1, o3 = o2 + v2;
  if (base + 3 < n) {
    *(int4*)(rp + base) = make_int4(o0, o1, o2, o3);
  } else if (base < n) {
    rp[base] = o0;
    if (base + 1 < n) rp[base + 1] = o1;
    if (base + 2 < n) rp[base + 2] = o2;
  }
  if (t == 255) bsum[blockIdx.x] = woff + incl;  // block total
}

// exclusive scan of <=256 block sums; writes grand total to rp[n]
__global__ void scan2_kernel(int* __restrict__ bsum, int nb, int* __restrict__ rp_end) {
  __shared__ int s[256];
  int t = threadIdx.x;
  int v = (t < nb) ? bsum[t] : 0;
  s[t] = v;
  __syncthreads();
  int val = v;
  for (int off = 1; off < 256; off <<= 1) {
    int add = (t >= off) ? s[t - off] : 0;
    __syncthreads();
    val += add;
    s[t] = val;
    __syncthreads();
  }
  if (t < nb) bsum[t] = val - v;  // exclusive
  if (t == 255) *rp_end = val;    // total
}

__global__ void scan3_kernel(int* __restrict__ rp, const int* __restrict__ bsum, int n) {
  int i = blockIdx.x * 256 + threadIdx.x;
  if (i < n) rp[i] += bsum[i >> 10];
}

// ---- degree sort (counting sort by min(deg,255)) -> vorder ----

__global__ void dhist_kernel(const int* __restrict__ cnt, int* __restrict__ dh, int n) {
  int i = blockIdx.x * 256 + threadIdx.x;
  if (i < n) atomicAdd(&dh[min(cnt[i], 255)], 1);
}

__global__ void dscan_kernel(const int* __restrict__ dh, int* __restrict__ dcur) {
  __shared__ int s[256];
  int t = threadIdx.x;
  int v = dh[t];
  s[t] = v;
  __syncthreads();
  int val = v;
  for (int off = 1; off < 256; off <<= 1) {
    int add = (t >= off) ? s[t - off] : 0;
    __syncthreads();
    val += add;
    s[t] = val;
    __syncthreads();
  }
  dcur[t] = val - v;  // exclusive base, doubles as cursor
}

__global__ void dscat_kernel(const int* __restrict__ cnt, int* __restrict__ dcur,
                             int* __restrict__ vorder, int n) {
  int i = blockIdx.x * 256 + threadIdx.x;
  if (i < n) {
    int b = min(cnt[i], 255);
    int p = atomicAdd(&dcur[b], 1);
    vorder[p] = i;
  }
}

// ---- bucketed two-pass edge scatter (bucket = dst>>11, col window L2-resident)

__global__ void gcur_init_kernel(const int* __restrict__ rp, int* __restrict__ gcur, int n) {
  int t = threadIdx.x;  // 1 block, 64 threads
  if (t < 64) gcur[t] = rp[min(t << 11, n)];
}

__global__ void scat1_kernel(const int* __restrict__ src, const int* __restrict__ dst,
                             int* __restrict__ gcur, uint2* __restrict__ ebuf, int e) {
  __shared__ int lh[64], lb[64];
  int t = threadIdx.x;
  if (t < 64) lh[t] = 0;
  __syncthreads();
  int base = blockIdx.x * 4096;
  int d[16], rk[16];
  #pragma unroll
  for (int j = 0; j < 16; ++j) {
    int i = base + j * 256 + t;
    if (i < e) {
      d[j] = dst[i];
      rk[j] = atomicAdd(&lh[min(d[j] >> 11, 63)], 1);
    }
  }
  __syncthreads();
  if (t < 64 && lh[t] > 0) lb[t] = atomicAdd(&gcur[t], lh[t]);
  __syncthreads();
  #pragma unroll
  for (int j = 0; j < 16; ++j) {
    int i = base + j * 256 + t;
    if (i < e)
      ebuf[lb[min(d[j] >> 11, 63)] + rk[j]] = make_uint2((unsigned)src[i], (unsigned)d[j]);
  }
}

__global__ void scat2_kernel(const uint2* __restrict__ ebuf, const int* __restrict__ rp,
                             int* __restrict__ cur, int* __restrict__ col, int e) {
  int i = blockIdx.x * 256 + threadIdx.x;
  if (i < e) {
    uint2 p = ebuf[i];
    int d = (int)p.y;
    int q = rp[d] + atomicAdd(&cur[d], 1);
    col[q] = (int)p.x;
  }
}

// ---------------- protein GNN ----------------
// g_k = nrm.*h_k stored fp16 in 16-feat chunks, padded width PD=ceil(DIN/16)*16
// (pads stay zero). Slab k (hop k) at gbase + k*slabh, slabh = n*80 halves.
// Chunk c, node v, slot s: addr = (c*n + v)*16 + s  (32B rows, L2-friendly).
// gathers: g_k = nrm^2 * sum_{src} g_{k-1}[src], one L2-resident chunk/pass;
// nodes processed in degree-sorted order (vorder) so each wave's 4 nodes have
// near-equal degree (removes max-of-4 slot waste) + wave-uniform early break.
// combine: block = 64 nodes; 4 waves each own a wave-uniform quarter of DOUT
// (W via scalar loads); cross-wave l2norm via LDS; writes next g0 in-place.

__device__ __forceinline__ float2 cvt_h2(uint32_t u) {
  __half2 h = *reinterpret_cast<__half2*>(&u);
  return make_float2(__low2float(h), __high2float(h));
}

// grid = NPASS*nbn (pass-major); 256 thr = 4 waves; wave = 4 nodes x 16 lanes
// (4 edge slots x 4 f4-lanes, 8B loads); 4 clamped branch-free loads in flight.
__global__ void gather_all_kernel(const __half* __restrict__ gin, const int* __restrict__ rp,
                                  const int* __restrict__ col, const float* __restrict__ nrm,
                                  const int* __restrict__ vorder,
                                  __half* __restrict__ gout, int n, int nbn) {
  int pass = blockIdx.x / nbn;
  int bid = blockIdx.x - pass * nbn;
  int lane = threadIdx.x & 63, wv = threadIdx.x >> 6;
  int q = lane >> 4, r = lane & 15;
  int e_slot = r >> 2, f4 = r & 3;
  int vi = bid * 16 + wv * 4 + q;
  bool vok = (vi < n);
  int v = vok ? vorder[vi] : 0;
  int beg = 0, deg = 0;
  if (vok) { beg = rp[v]; deg = rp[v + 1] - beg; }
  const __half* gc = gin + (size_t)pass * n * 16;
  __half* go = gout + (size_t)pass * n * 16;
  float a0 = 0.f, a1 = 0.f, a2 = 0.f, a3 = 0.f;
  for (int base = 0; __any(base < deg); base += 16) {
    int ec = (base + r < deg) ? col[beg + base + r] : -1;
    #pragma unroll
    for (int js = 0; js < 16; js += 4) {
      if (js > 0 && __all(base + js >= deg)) break;   // sorted degs -> coherent
      int sl = (q << 4) + js + e_slot;
      int s0 = __shfl(ec, sl, 64);
      int idx = (s0 >= 0) ? s0 : 0;             // clamped: row 0 when invalid
      float m = (s0 >= 0) ? 1.f : 0.f;
      uint2 u = *(const uint2*)(gc + (size_t)idx * 16 + (f4 << 2));
      float2 p0 = cvt_h2(u.x), p1 = cvt_h2(u.y);
      a0 = fmaf(m, p0.x, a0); a1 = fmaf(m, p0.y, a1);
      a2 = fmaf(m, p1.x, a2); a3 = fmaf(m, p1.y, a3);
    }
  }
  a0 += __shfl_xor(a0, 4, 64);  a1 += __shfl_xor(a1, 4, 64);
  a2 += __shfl_xor(a2, 4, 64);  a3 += __shfl_xor(a3, 4, 64);
  a0 += __shfl_xor(a0, 8, 64);  a1 += __shfl_xor(a1, 8, 64);
  a2 += __shfl_xor(a2, 8, 64);  a3 += __shfl_xor(a3, 8, 64);
  if (vok && e_slot == 0) {
    float nm = nrm[v];
    float nm2 = nm * nm;
    __half2 w0 = __floats2half2_rn(a0 * nm2, a1 * nm2);
    __half2 w1 = __floats2half2_rn(a2 * nm2, a3 * nm2);
    uint2 st;
    st.x = *reinterpret_cast<uint32_t*>(&w0);
    st.y = *reinterpret_cast<uint32_t*>(&w1);
    *(uint2*)(go + ((size_t)v << 4) + (f4 << 2)) = st;
  }
}

// layer-1 only: g0 = x * nrm (chunked, pads zero)
template<int DIN>
__global__ void init_g0_kernel(const float* __restrict__ x, const float* __restrict__ nrm,
                               __half* __restrict__ g0, int n) {
  constexpr int PD = (DIN + 15) & ~15;
  int lane = threadIdx.x & 63;
  int v = blockIdx.x * 4 + (threadIdx.x >> 6);
  if (v >= n) return;
  float nm = nrm[v];
  for (int f = lane; f < PD; f += 64) {
    float val = (f < DIN) ? x[(size_t)v * DIN + f] * nm : 0.f;
    g0[(((size_t)(f >> 4) * n + v) << 4) + (f & 15)] = __float2half(val);
  }
}

// pad W [5*DIN][DOUT] -> Wp [5*PD][DOUT] (pad rows zero)
__global__ void padw_kernel(const float* __restrict__ W, float* __restrict__ Wp,
                            int din, int dout, int pd) {
  int i = blockIdx.x * 256 + threadIdx.x;
  int total = 5 * pd * dout;
  if (i >= total) return;
  int f = i / dout, j = i - f * dout;
  int hop = f / pd, rem = f - hop * pd;
  Wp[i] = (rem < din) ? W[(size_t)(hop * din + rem) * dout + j] : 0.f;
}

// combine v4: block = 64 nodes, wave wv owns outputs [wv*QO, ...) (wave-uniform
// column offset -> W/bias scalar loads). Cross-wave l2norm via LDS ssq.
template<int DIN, int DOUT, bool LAST>
__global__ __launch_bounds__(256) void combine_kernel(
    const __half* __restrict__ gbase, const float* __restrict__ nrm,
    const float* __restrict__ Wp, const float* __restrict__ bias,
    __half* __restrict__ gnext, float* __restrict__ Xout, int n) {
  constexpr int PD  = (DIN + 15) & ~15;
  constexpr int NCH = PD / 16;
  constexpr int PDN = (DOUT + 15) & ~15;
  constexpr int QO  = ((DOUT + 7) / 8) * 2;   // even, 4*QO >= DOUT
  __shared__ float ssq[4 * 64];
  int lane = threadIdx.x & 63, wv = threadIdx.x >> 6;
  int v = blockIdx.x * 64 + lane;
  bool vok = (v < n);
  int vc = vok ? v : 0;
  const size_t slabh = (size_t)n * 80;
  int cofs = __builtin_amdgcn_readfirstlane(wv) * QO;   // wave-uniform
  float acc[QO];
  #pragma unroll
  for (int jj = 0; jj < QO; ++jj) acc[jj] = 0.f;
  const float* wb = Wp + cofs;
  for (int hop = 0; hop < 5; ++hop) {
    const __half* hrow = gbase + (size_t)hop * slabh + ((size_t)vc << 4);
    #pragma unroll 1
    for (int ch = 0; ch < NCH; ++ch) {
      uint4 u0 = *(const uint4*)hrow;
      uint4 u1 = *(const uint4*)(hrow + 8);
      float h[16];
      {
        float2 p;
        p = cvt_h2(u0.x); h[0] = p.x; h[1] = p.y;
        p = cvt_h2(u0.y); h[2] = p.x; h[3] = p.y;
        p = cvt_h2(u0.z); h[4] = p.x; h[5] = p.y;
        p = cvt_h2(u0.w); h[6] = p.x; h[7] = p.y;
        p = cvt_h2(u1.x); h[8] = p.x; h[9] = p.y;
        p = cvt_h2(u1.y); h[10] = p.x; h[11] = p.y;
        p = cvt_h2(u1.z); h[12] = p.x; h[13] = p.y;
        p = cvt_h2(u1.w); h[14] = p.x; h[15] = p.y;
      }
      #pragma unroll
      for (int s = 0; s < 16; ++s) {
        #pragma unroll
        for (int jj = 0; jj < QO; ++jj) acc[jj] += h[s] * wb[s * DOUT + jj];
      }
      wb += 16 * DOUT;
      hrow += ((size_t)n << 4);
    }
  }
  float rn = 1.f / nrm[vc];
  float ss = 0.f;
  #pragma unroll
  for (int jj = 0; jj < QO; ++jj) {
    int j = cofs + jj;
    float y = (j < DOUT) ? fmaxf(bias[j] + acc[jj] * rn, 0.f) : 0.f;
    acc[jj] = y;
    ss += y * y;
  }
  ssq[wv * 64 + lane] = ss;
  __syncthreads();          // also orders all slab-0 reads before in-place writes
  if (!vok) return;
  float tot = ssq[lane] + ssq[64 + lane] + ssq[128 + lane] + ssq[192 + lane];
  float sc = 1.f / fmaxf(sqrtf(tot), 1e-12f);
  if (LAST) {
    #pragma unroll
    for (int jj = 0; jj < QO; ++jj) {
      int j = cofs + jj;
      if (j < DOUT) Xout[(size_t)v * DOUT + j] = acc[jj] * sc;
    }
  } else {
    float nm = nrm[v];
    #pragma unroll
    for (int jj = 0; jj < QO; jj += 2) {
      int j0 = cofs + jj;
      float a = (j0 < DOUT) ? acc[jj] * sc * nm : 0.f;
      float b = (j0 + 1 < DOUT) ? acc[jj + 1] * sc * nm : 0.f;
      int ch = j0 >> 4, s = j0 & 15;
      *(__half2*)(gnext + (((size_t)ch * n + v) << 4) + s) = __floats2half2_rn(a, b);
    }
    if (wv == 3) {
      #pragma unroll
      for (int j0 = 4 * QO; j0 < PDN; j0 += 2) {    // zero-fill padded tail
        int ch = j0 >> 4, s = j0 & 15;
        *(__half2*)(gnext + (((size_t)ch * n + v) << 4) + s) = __floats2half2_rn(0.f, 0.f);
      }
    }
  }
}

// ---------------- ligand GNN: small-n fused hop (g is L2-resident) --------

template<int DIN, int GS, int DOUT>
__global__ void init_gemm_kernel(const float* __restrict__ x, const float* __restrict__ nrm,
                                 const float* __restrict__ W, const float* __restrict__ bias,
                                 __half* __restrict__ gout, float* __restrict__ y, int n) {
  int lane = threadIdx.x & 63;
  int v = blockIdx.x * 4 + (threadIdx.x >> 6);
  if (v >= n) return;
  float nm = nrm[v];
  const float* xr = x + (size_t)v * DIN;
  float hA = (lane < DIN) ? xr[lane] : 0.f;
  float hB = 0.f;
  if constexpr (DIN > 64) { if (lane + 64 < DIN) hB = xr[lane + 64]; }
  __half* go = gout + (size_t)v * GS;
  if (lane < DIN) go[lane] = __float2half(hA * nm);
  if constexpr (DIN > 64) { if (lane + 64 < DIN) go[lane + 64] = __float2half(hB * nm); }
  int cl = (lane < DOUT) ? lane : 0;
  float acc = bias[cl];
  const float* Wk = W + cl;
  #pragma unroll
  for (int f = 0; f < DIN; ++f) {
    float hf = (f < 64) ? __shfl(hA, f, 64) : __shfl(hB, f - 64, 64);
    acc += hf * Wk[(size_t)f * DOUT];
  }
  if (lane < DOUT) y[(size_t)v * DOUT + lane] = acc;
}

template<int DIN, int GS, int DOUT, bool WRITEG, bool FINAL>
__global__ void fused_hop_kernel(const __half* __restrict__ gin, const int* __restrict__ rp,
                                 const int* __restrict__ col, const float* __restrict__ nrm,
                                 const float* __restrict__ W, __half* __restrict__ gout,
                                 float* __restrict__ y, float* __restrict__ Xout,
                                 int k, int n) {
  int lane = threadIdx.x & 63;
  int v = blockIdx.x * 4 + (threadIdx.x >> 6);
  if (v >= n) return;
  int beg = rp[v], end = rp[v + 1];
  float a0 = 0.f, a1 = 0.f;
  for (int base = beg; base < end; base += 64) {
    int m = end - base; if (m > 64) m = 64;
    int myc = (lane < m) ? col[base + lane] : 0;
    int j = 0;
    for (; j + 8 <= m; j += 8) {
      int ss[8];
      float t0[8], t1[8];
      #pragma unroll
      for (int u = 0; u < 8; ++u) ss[u] = __shfl(myc, j + u, 64);
      #pragma unroll
      for (int u = 0; u < 8; ++u) {
        const __half* rr = gin + (size_t)ss[u] * GS;
        t0[u] = (lane < DIN) ? __half2float(rr[lane]) : 0.f;
        if constexpr (DIN > 64) t1[u] = (lane + 64 < DIN) ? __half2float(rr[lane + 64]) : 0.f;
      }
      #pragma unroll
      for (int u = 0; u < 8; ++u) {
        a0 += t0[u];
        if constexpr (DIN > 64) a1 += t1[u];
      }
    }
    for (; j < m; ++j) {
      int s = __shfl(myc, j, 64);
      const __half* rr = gin + (size_t)s * GS;
      if (lane < DIN) a0 += __half2float(rr[lane]);
      if constexpr (DIN > 64) { if (lane + 64 < DIN) a1 += __half2float(rr[lane + 64]); }
    }
  }
  float nm = nrm[v];
  float hA = a0 * nm, hB = a1 * nm;
  if (WRITEG) {
    __half* go = gout + (size_t)v * GS;
    if (lane < DIN) go[lane] = __float2half(hA * nm);
    if constexpr (DIN > 64) { if (lane + 64 < DIN) go[lane + 64] = __float2half(hB * nm); }
  }
  int cl = (lane < DOUT) ? lane : 0;
  float acc = 0.f;
  if (lane < DOUT) acc = y[(size_t)v * DOUT + lane];
  const float* Wk = W + (size_t)k * DIN * DOUT + cl;
  #pragma unroll
  for (int f = 0; f < DIN; ++f) {
    float hf = (f < 64) ? __shfl(hA, f, 64) : __shfl(hB, f - 64, 64);
    acc += hf * Wk[(size_t)f * DOUT];
  }
  if constexpr (FINAL) {
    float val = (lane < DOUT) ? fmaxf(acc, 0.f) : 0.f;
    float ss2 = val * val;
    #pragma unroll
    for (int off2 = 32; off2 > 0; off2 >>= 1) ss2 += __shfl_xor(ss2, off2, 64);
    float scale = 1.f / fmaxf(sqrtf(ss2), 1e-12f);
    if (lane < DOUT) Xout[(size_t)v * DOUT + lane] = val * scale;
  } else {
    if (lane < DOUT) y[(size_t)v * DOUT + lane] = acc;
  }
}

// hierarchical segment-max (values >= 0 post relu+l2norm; rep zeroed first)
__global__ void segmax_kernel(const float* __restrict__ X, const int* __restrict__ gid,
                              float* __restrict__ rep, int n, int row_off) {
  __shared__ float tab[4][45];
  __shared__ int gids[256];
  int t = threadIdx.x;
  for (int i = t; i < 4 * 45; i += 256) ((float*)tab)[i] = 0.f;
  int v0 = blockIdx.x * 256;
  int vend = v0 + 256; if (vend > n) vend = n;
  int nv = vend - v0;
  if (t < nv) gids[t] = gid[v0 + t];
  __syncthreads();
  int g0 = gids[0];
  int total = nv * 45;
  for (int i = t; i < total; i += 256) {
    int vl = i / 45, j = i - vl * 45;
    float val = X[(size_t)(v0 + vl) * 45 + j];
    int rel = gids[vl] - g0;
    if (rel >= 0 && rel < 4)
      atomicMax((unsigned int*)&tab[rel][j], __float_as_uint(val));
    else
      atomicMax((unsigned int*)&rep[(size_t)(row_off + gids[vl]) * 45 + j], __float_as_uint(val));
  }
  __syncthreads();
  for (int i = t; i < 4 * 45; i += 256) {
    float val = ((float*)tab)[i];
    if (val > 0.f) {
      int rel = i / 45, j = i - rel * 45;
      atomicMax((unsigned int*)&rep[(size_t)(row_off + g0 + rel) * 45 + j], __float_as_uint(val));
    }
  }
}

// ---------------- attention ----------------

__global__ void qkv_kernel(const float* __restrict__ rep, const float* __restrict__ w,
                           const float* __restrict__ b, float* __restrict__ qkv) {
  int i = blockIdx.x;      // 0..129
  int t = threadIdx.x;     // 256
  __shared__ float sr[45];
  if (t < 45) sr[t] = (i < 65) ? rep[(size_t)i * 45 + t] : 0.f;
  __syncthreads();
  if (t < 135) {
    float acc = b[t];
    #pragma unroll 5
    for (int d = 0; d < 45; ++d) acc += sr[d] * w[d * 135 + t];
    qkv[(size_t)i * 135 + t] = acc;
  }
}

__global__ void attn_kernel(const float* __restrict__ qkv, const float* __restrict__ proj_w,
                            const float* __restrict__ proj_b, float* __restrict__ ctx) {
  int i = blockIdx.x;     // query row
  int t = threadIdx.x;    // 256
  __shared__ float q[45];
  __shared__ float p[130];
  __shared__ float red[256];
  __shared__ float ao[45];
  if (t < 45) q[t] = qkv[(size_t)i * 135 + t];
  __syncthreads();
  float s = -1e30f;
  if (t < 130) {
    int j = t;
    float dot = 0.f;
    #pragma unroll 5
    for (int d = 0; d < 45; ++d) dot += q[d] * qkv[(size_t)j * 135 + 45 + d];
    dot *= 0.14907119849998599f;  // 45^-0.5
    bool mz;  // mask == 0 ?
    if (i == 64 && j == 64) mz = true;
    else if (i == 64 || j == 64) mz = false;
    else mz = !(i == j && i < 65);
    s = mz ? -1e9f : dot;
  }
  red[t] = s;
  __syncthreads();
  #pragma unroll
  for (int off = 128; off > 0; off >>= 1) {
    if (t < off) red[t] = fmaxf(red[t], red[t + off]);
    __syncthreads();
  }
  float mx = red[0];
  __syncthreads();
  float e = (t < 130) ? expf(s - mx) : 0.f;
  red[t] = e;
  __syncthreads();
  #pragma unroll
  for (int off = 128; off > 0; off >>= 1) {
    if (t < off) red[t] += red[t + off];
    __syncthreads();
  }
  float denom = red[0];
  __syncthreads();
  if (t < 130) p[t] = e / denom;
  __syncthreads();
  if (t < 45) {
    float acc = 0.f;
    for (int j = 0; j < 130; ++j) acc += p[j] * qkv[(size_t)j * 135 + 90 + t];
    ao[t] = acc;
  }
  __syncthreads();
  if (t < 45) {
    float pr = proj_b[t];
    #pragma unroll 5
    for (int e2 = 0; e2 < 45; ++e2) pr += ao[e2] * proj_w[e2 * 45 + t];
    ctx[(size_t)i * 45 + t] = pr;
  }
}

// ---------------- head MLP ----------------

__global__ void bias_init_kernel(const float* __restrict__ b, float* __restrict__ out, int n) {
  int i = blockIdx.x * 256 + threadIdx.x;
  if (i < n) out[i] = b[i];
}

template<bool RELU_IN>
__global__ void fc_splitk_kernel(const float* __restrict__ x, const float* __restrict__ W,
                                 float* __restrict__ out, int nin, int nout, int kchunk) {
  __shared__ float xs[1024];
  int k0 = blockIdx.y * kchunk;
  int k1 = k0 + kchunk; if (k1 > nin) k1 = nin;
  int len = k1 - k0;
  for (int i = threadIdx.x; i < len; i += blockDim.x) {
    float v = x[k0 + i];
    xs[i] = RELU_IN ? fmaxf(v, 0.f) : v;
  }
  __syncthreads();
  int j = blockIdx.x * blockDim.x + threadIdx.x;
  if (j < nout) {
    float acc = 0.f;
    const float* Wp = W + (size_t)k0 * nout + j;
    for (int i = 0; i < len; ++i) acc += xs[i] * Wp[(size_t)i * nout];
    atomicAdd(&out[j], acc);
  }
}

__global__ void final_fc_kernel(const float* __restrict__ x, const float* __restrict__ W,
                                const float* __restrict__ b, float* __restrict__ out) {
  __shared__ float red[512];
  int t = threadIdx.x;
  float acc = 0.f;
  if (t < 500) acc = fmaxf(x[t], 0.f) * W[t];
  red[t] = acc;
  __syncthreads();
  #pragma unroll
  for (int off = 256; off > 0; off >>= 1) {
    if (t < off) red[t] += red[t + off];
    __syncthreads();
  }
  if (t == 0) {
    float z = red[0] + b[0];
    out[0] = 1.f / (1.f + expf(-z));
  }
}

// ---------------- host-side orchestration ----------------

struct Bufs {
  __half* slabs;         // protein: 5 slabs of n*80 halves
  __half *ligA, *ligB;   // ligand ping/pong
  float *X, *Y, *nrm, *Wp;
  int *cnt, *cur, *rp, *col, *bsum, *vorder, *dh, *dcur, *gcur;
  uint2* ebuf;           // aliases slabs (only live during build_csr)
};

template<int DIN, int DOUT, bool LAST>
void run_layer_prot(const Bufs& g, const float* W, const float* b, int n, hipStream_t st) {
  constexpr int PD = (DIN + 15) & ~15;
  constexpr int NPASS = PD / 16;
  int nbn = (n + 15) / 16;
  size_t slabh = (size_t)n * 80;
  for (int k = 1; k <= 4; ++k)
    gather_all_kernel<<<NPASS * nbn, 256, 0, st>>>(g.slabs + (size_t)(k - 1) * slabh,
                                                   g.rp, g.col, g.nrm, g.vorder,
                                                   g.slabs + (size_t)k * slabh, n, nbn);
  int wtotal = 5 * PD * DOUT;
  padw_kernel<<<(wtotal + 255) / 256, 256, 0, st>>>(W, g.Wp, DIN, DOUT, PD);
  combine_kernel<DIN, DOUT, LAST><<<(n + 63) / 64, 256, 0, st>>>(
      g.slabs, g.nrm, g.Wp, b, g.slabs, g.X, n);
}

template<int DIN, int GS, int DOUT>
void run_layer_lig(const float* xin, const Bufs& g, const float* W, const float* b,
                   int n, hipStream_t st) {
  int nb = (n + 3) / 4;
  init_gemm_kernel<DIN, GS, DOUT><<<nb, 256, 0, st>>>(xin, g.nrm, W, b, g.ligA, g.Y, n);
  const __half* gin = g.ligA;
  __half* gout = g.ligB;
  for (int k = 1; k <= 4; ++k) {
    if (k < 4)
      fused_hop_kernel<DIN, GS, DOUT, true, false><<<nb, 256, 0, st>>>(gin, g.rp, g.col, g.nrm, W, gout, g.Y, g.X, k, n);
    else
      fused_hop_kernel<DIN, GS, DOUT, false, true><<<nb, 256, 0, st>>>(gin, g.rp, g.col, g.nrm, W, gout, g.Y, g.X, 4, n);
    __half* t = (__half*)gin; gin = gout; gout = t;
  }
}

void build_csr(const int* src, const int* dst, const Bufs& g, int n, int e, hipStream_t st) {
  hipMemsetAsync(g.cnt, 0, (size_t)n * 4, st);
  hipMemsetAsync(g.cur, 0, (size_t)n * 4, st);
  hipMemsetAsync(g.dh, 0, 256 * 4, st);
  hist_kernel<<<(e + 255) / 256, 256, 0, st>>>(dst, g.cnt, e);
  int nb1 = (n + 1023) / 1024;
  scan1_kernel<<<nb1, 256, 0, st>>>(g.cnt, g.rp, g.bsum, g.nrm, n);
  scan2_kernel<<<1, 256, 0, st>>>(g.bsum, nb1, g.rp + n);
  scan3_kernel<<<(n + 255) / 256, 256, 0, st>>>(g.rp, g.bsum, n);
  // degree sort -> vorder
  dhist_kernel<<<(n + 255) / 256, 256, 0, st>>>(g.cnt, g.dh, n);
  dscan_kernel<<<1, 256, 0, st>>>(g.dh, g.dcur);
  dscat_kernel<<<(n + 255) / 256, 256, 0, st>>>(g.cnt, g.dcur, g.vorder, n);
  // bucketed two-pass scatter (col writes stay in L2-resident windows)
  gcur_init_kernel<<<1, 64, 0, st>>>(g.rp, g.gcur, n);
  scat1_kernel<<<(e + 4095) / 4096, 256, 0, st>>>(src, dst, g.gcur, g.ebuf, e);
  scat2_kernel<<<(e + 255) / 256, 256, 0, st>>>(g.ebuf, g.rp, g.cur, g.col, e);
}

} // namespace

extern "C" void kernel_launch(void* const* d_in, const int* in_sizes, int n_in,
                              void* d_out, int out_size, void* d_ws, size_t ws_size,
                              hipStream_t stream) {
  (void)in_sizes; (void)n_in; (void)out_size;

  const float* prot_x = (const float*)d_in[0];
  const float* lig_x  = (const float*)d_in[1];
  const float* pW[3] = {(const float*)d_in[2], (const float*)d_in[4], (const float*)d_in[6]};
  const float* pB[3] = {(const float*)d_in[3], (const float*)d_in[5], (const float*)d_in[7]};
  const float* lW[4] = {(const float*)d_in[8], (const float*)d_in[10], (const float*)d_in[12], (const float*)d_in[14]};
  const float* lB[4] = {(const float*)d_in[9], (const float*)d_in[11], (const float*)d_in[13], (const float*)d_in[15]};
  const float* qkv_w = (const float*)d_in[16];
  const float* qkv_b = (const float*)d_in[17];
  const float* proj_w = (const float*)d_in[18];
  const float* proj_b = (const float*)d_in[19];
  const float* h0_w = (const float*)d_in[20];
  const float* h0_b = (const float*)d_in[21];
  const float* h1_w = (const float*)d_in[22];
  const float* h1_b = (const float*)d_in[23];
  const float* h2_w = (const float*)d_in[24];
  const float* h2_b = (const float*)d_in[25];
  const float* fc_w = (const float*)d_in[26];
  const float* fc_b = (const float*)d_in[27];
  const int* prot_src = (const int*)d_in[28];
  const int* prot_dst = (const int*)d_in[29];
  const int* prot_gid = (const int*)d_in[30];
  const int* lig_src  = (const int*)d_in[31];
  const int* lig_dst  = (const int*)d_in[32];
  const int* lig_gid  = (const int*)d_in[33];

  // workspace carve-up
  char* w = (char*)d_ws;
  size_t off = 0;
  auto alloc = [&](size_t bytes) -> void* {
    void* p = w + off;
    off += (bytes + 255) & ~(size_t)255;
    return p;
  };
  __half* slabs = (__half*)alloc((size_t)5 * NPROT * 80 * 2);   // 80 MB: g0..g4
  __half* ligA  = (__half*)alloc((size_t)NLIG * 96 * 2);
  __half* ligB  = (__half*)alloc((size_t)NLIG * 96 * 2);
  float* X   = (float*)alloc((size_t)NPROT * 45 * 4);
  float* Y   = (float*)alloc((size_t)NLIG * 50 * 4);
  float* nrm = (float*)alloc((size_t)NPROT * 4);
  float* Wp  = (float*)alloc((size_t)5 * 80 * 50 * 4 + 256);  // + scalar-OOB pad
  int* cnt   = (int*)alloc((size_t)NPROT * 4);
  int* cur   = (int*)alloc((size_t)NPROT * 4);
  int* rp    = (int*)alloc(((size_t)NPROT + 1) * 4);
  int* colb  = (int*)alloc((size_t)EPROT * 4);
  int* bsum  = (int*)alloc((size_t)256 * 4);
  int* vorder = (int*)alloc((size_t)NPROT * 4);
  int* dh    = (int*)alloc((size_t)256 * 4);
  int* dcur  = (int*)alloc((size_t)256 * 4);
  int* gcur  = (int*)alloc((size_t)64 * 4);
  float* rep = (float*)alloc((size_t)65 * 45 * 4);
  float* qkvb = (float*)alloc((size_t)130 * 135 * 4);
  float* ctx  = (float*)alloc((size_t)5850 * 4);
  float* hb0  = (float*)alloc((size_t)2000 * 4);
  float* hb1  = (float*)alloc((size_t)1000 * 4);
  float* hb2  = (float*)alloc((size_t)500 * 4);
  if (off > ws_size) return;  // workspace too small: fail loudly via validation

  hipMemsetAsync(rep, 0, (size_t)65 * 45 * 4, stream);

  Bufs g{slabs, ligA, ligB, X, Y, nrm, Wp, cnt, cur, rp, colb, bsum,
         vorder, dh, dcur, gcur, (uint2*)slabs /*ebuf aliases slabs*/};

  // ---- protein GNN (chunked L2-resident gathers + wave-split combine) ----
  build_csr(prot_src, prot_dst, g, NPROT, EPROT, stream);   // ebuf uses slabs (dead here)
  init_g0_kernel<74><<<(NPROT + 3) / 4, 256, 0, stream>>>(prot_x, g.nrm, g.slabs, NPROT);
  run_layer_prot<74, 50, false>(g, pW[0], pB[0], NPROT, stream);
  run_layer_prot<50, 45, false>(g, pW[1], pB[1], NPROT, stream);
  run_layer_prot<45, 45, true >(g, pW[2], pB[2], NPROT, stream);
  segmax_kernel<<<(NPROT + 255) / 256, 256, 0, stream>>>(g.X, prot_gid, rep, NPROT, 1);

  // ---- ligand GNN (small; fused path; slabs dead again -> ebuf reuse ok) ----
  build_csr(lig_src, lig_dst, g, NLIG, ELIG, stream);
  run_layer_lig<74, 96, 50>(lig_x, g, lW[0], lB[0], NLIG, stream);
  run_layer_lig<50, 64, 45>(g.X, g, lW[1], lB[1], NLIG, stream);
  run_layer_lig<45, 64, 45>(g.X, g, lW[2], lB[2], NLIG, stream);
  run_layer_lig<45, 64, 45>(g.X, g, lW[3], lB[3], NLIG, stream);
  segmax_kernel<<<(NLIG + 255) / 256, 256, 0, stream>>>(g.X, lig_gid, rep, NLIG, 0);

  // ---- attention ----
  qkv_kernel<<<130, 256, 0, stream>>>(rep, qkv_w, qkv_b, qkvb);
  attn_kernel<<<130, 256, 0, stream>>>(qkvb, proj_w, proj_b, ctx);

  // ---- head MLP ----
  bias_init_kernel<<<8, 256, 0, stream>>>(h0_b, hb0, 2000);
  fc_splitk_kernel<false><<<dim3(8, 8), 256, 0, stream>>>(ctx, h0_w, hb0, 5850, 2000, 732);
  bias_init_kernel<<<4, 256, 0, stream>>>(h1_b, hb1, 1000);
  fc_splitk_kernel<true><<<dim3(4, 4), 256, 0, stream>>>(hb0, h1_w, hb1, 2000, 1000, 500);
  bias_init_kernel<<<2, 256, 0, stream>>>(h2_b, hb2, 500);
  fc_splitk_kernel<true><<<dim3(2, 2), 256, 0, stream>>>(hb1, h2_w, hb2, 1000, 500, 500);
  final_fc_kernel<<<1, 512, 0, stream>>>(hb2, fc_w, fc_b, (float*)d_out);
}

// Round 12
// 1480.794 us; speedup vs baseline: 1.4423x; 1.4423x over previous
//
#include <hip/hip_runtime.h>
#include <hip/hip_fp16.h>
#include <cstddef>
#include <cstdint>

namespace {

constexpr int NPROT = 100000;
constexpr int EPROT = 1600000;
constexpr int NLIG  = 5000;
constexpr int ELIG  = 80000;

// ---------------- CSR construction ----------------

__global__ void hist_kernel(const int* __restrict__ dst, int* __restrict__ cnt, int e) {
  int i = blockIdx.x * 256 + threadIdx.x;
  if (i < e) atomicAdd(&cnt[dst[i]], 1);
}

// per-block (1024 elems) exclusive scan; also computes nrm = max(deg,1)^-0.5
__global__ void scan1_kernel(const int* __restrict__ cnt, int* __restrict__ rp,
                             int* __restrict__ bsum, float* __restrict__ nrm, int n) {
  __shared__ int wsum[4];
  int t = threadIdx.x;
  int base = blockIdx.x * 1024 + t * 4;
  int v0 = 0, v1 = 0, v2 = 0, v3 = 0;
  if (base + 3 < n) {
    int4 val = *(const int4*)(cnt + base);
    v0 = val.x; v1 = val.y; v2 = val.z; v3 = val.w;
  } else if (base < n) {
    v0 = cnt[base];
    if (base + 1 < n) v1 = cnt[base + 1];
    if (base + 2 < n) v2 = cnt[base + 2];
  }
  if (base < n)     nrm[base]     = 1.0f / sqrtf(fmaxf((float)v0, 1.0f));
  if (base + 1 < n) nrm[base + 1] = 1.0f / sqrtf(fmaxf((float)v1, 1.0f));
  if (base + 2 < n) nrm[base + 2] = 1.0f / sqrtf(fmaxf((float)v2, 1.0f));
  if (base + 3 < n) nrm[base + 3] = 1.0f / sqrtf(fmaxf((float)v3, 1.0f));
  int ts = v0 + v1 + v2 + v3;
  int lane = t & 63, wv = t >> 6;
  int incl = ts;
  #pragma unroll
  for (int off = 1; off < 64; off <<= 1) {
    int o = __shfl_up(incl, off, 64);
    if (lane >= off) incl += o;
  }
  if (lane == 63) wsum[wv] = incl;
  __syncthreads();
  int woff = 0;
  #pragma unroll
  for (int i = 0; i < 4; ++i) if (i < wv) woff += wsum[i];
  int excl = woff + incl - ts;
  int o0 = excl, o1 = o0 + v0, o2 = o1 + v1, o3 = o2 + v2;
  if (base + 3 < n) {
    *(int4*)(rp + base) = make_int4(o0, o1, o2, o3);
  } else if (base < n) {
    rp[base] = o0;
    if (base + 1 < n) rp[base + 1] = o1;
    if (base + 2 < n) rp[base + 2] = o2;
  }
  if (t == 255) bsum[blockIdx.x] = woff + incl;  // block total
}

// exclusive scan of <=256 block sums; writes grand total to rp[n]
__global__ void scan2_kernel(int* __restrict__ bsum, int nb, int* __restrict__ rp_end) {
  __shared__ int s[256];
  int t = threadIdx.x;
  int v = (t < nb) ? bsum[t] : 0;
  s[t] = v;
  __syncthreads();
  int val = v;
  for (int off = 1; off < 256; off <<= 1) {
    int add = (t >= off) ? s[t - off] : 0;
    __syncthreads();
    val += add;
    s[t] = val;
    __syncthreads();
  }
  if (t < nb) bsum[t] = val - v;  // exclusive
  if (t == 255) *rp_end = val;    // total
}

__global__ void scan3_kernel(int* __restrict__ rp, const int* __restrict__ bsum, int n) {
  int i = blockIdx.x * 256 + threadIdx.x;
  if (i < n) rp[i] += bsum[i >> 10];
}

// ---- bucketed two-pass edge scatter (bucket = dst>>11, col window L2-resident)

__global__ void gcur_init_kernel(const int* __restrict__ rp, int* __restrict__ gcur, int n) {
  int t = threadIdx.x;  // 1 block, 64 threads
  if (t < 64) gcur[t] = rp[min(t << 11, n)];
}

__global__ void scat1_kernel(const int* __restrict__ src, const int* __restrict__ dst,
                             int* __restrict__ gcur, uint2* __restrict__ ebuf, int e) {
  __shared__ int lh[64], lb[64];
  int t = threadIdx.x;
  if (t < 64) lh[t] = 0;
  __syncthreads();
  int base = blockIdx.x * 4096;
  int d[16], rk[16];
  #pragma unroll
  for (int j = 0; j < 16; ++j) {
    int i = base + j * 256 + t;
    if (i < e) {
      d[j] = dst[i];
      rk[j] = atomicAdd(&lh[min(d[j] >> 11, 63)], 1);
    }
  }
  __syncthreads();
  if (t < 64 && lh[t] > 0) lb[t] = atomicAdd(&gcur[t], lh[t]);
  __syncthreads();
  #pragma unroll
  for (int j = 0; j < 16; ++j) {
    int i = base + j * 256 + t;
    if (i < e)
      ebuf[lb[min(d[j] >> 11, 63)] + rk[j]] = make_uint2((unsigned)src[i], (unsigned)d[j]);
  }
}

__global__ void scat2_kernel(const uint2* __restrict__ ebuf, const int* __restrict__ rp,
                             int* __restrict__ cur, int* __restrict__ col, int e) {
  int i = blockIdx.x * 256 + threadIdx.x;
  if (i < e) {
    uint2 p = ebuf[i];
    int d = (int)p.y;
    int q = rp[d] + atomicAdd(&cur[d], 1);
    col[q] = (int)p.x;
  }
}

// ---------------- protein GNN ----------------
// g_k = nrm.*h_k stored fp16 in 16-feat chunks, padded width PD=ceil(DIN/16)*16
// (pads stay zero). Slab k (hop k) at gbase + k*slabh, slabh = n*80 halves.
// Chunk c, node v, slot s: addr = (c*n + v)*16 + s  (32B rows, L2-friendly).
// gathers: g_k = nrm^2 * sum_{src} g_{k-1}[src], one L2-resident chunk/pass;
// inner tile accumulates in packed fp16 (v_pk_fma_f16), flushed to fp32 every
// 16-edge tile (<=4-term fp16 partials: error ~2^-11, same order as storage).
// combine: block = 64 nodes; 4 waves each own a wave-uniform quarter of DOUT
// (W via scalar loads); cross-wave l2norm via LDS; writes next g0 in-place.

__device__ __forceinline__ float2 cvt_h2(uint32_t u) {
  __half2 h = *reinterpret_cast<__half2*>(&u);
  return make_float2(__low2float(h), __high2float(h));
}

__device__ __forceinline__ __half2 u2h2(uint32_t u) {
  return *reinterpret_cast<__half2*>(&u);
}

// grid = NPASS*nbn (pass-major); 256 thr = 4 waves; wave = 4 nodes x 16 lanes
// (4 edge slots x 4 f4-lanes, 8B loads); 4 clamped branch-free loads in flight.
__global__ void gather_all_kernel(const __half* __restrict__ gin, const int* __restrict__ rp,
                                  const int* __restrict__ col, const float* __restrict__ nrm,
                                  __half* __restrict__ gout, int n, int nbn) {
  int pass = blockIdx.x / nbn;
  int bid = blockIdx.x - pass * nbn;
  int lane = threadIdx.x & 63, wv = threadIdx.x >> 6;
  int q = lane >> 4, r = lane & 15;
  int e_slot = r >> 2, f4 = r & 3;
  int v = bid * 16 + wv * 4 + q;
  bool vok = (v < n);
  int beg = 0, deg = 0;
  if (vok) { beg = rp[v]; deg = rp[v + 1] - beg; }
  const __half* gc = gin + (size_t)pass * n * 16;
  __half* go = gout + (size_t)pass * n * 16;
  const uint32_t ONE2 = 0x3C003C00u;   // {1.0h, 1.0h}
  float a0 = 0.f, a1 = 0.f, a2 = 0.f, a3 = 0.f;
  for (int base = 0; __any(base < deg); base += 16) {
    int ec = (base + r < deg) ? col[beg + base + r] : -1;
    __half2 p0 = u2h2(0u), p1 = u2h2(0u);
    #pragma unroll
    for (int js = 0; js < 16; js += 4) {
      if (js > 0 && __all(base + js >= deg)) break;
      int sl = (q << 4) + js + e_slot;
      int s0 = __shfl(ec, sl, 64);
      int idx = (s0 >= 0) ? s0 : 0;             // clamped: row 0 when invalid
      uint32_t mh = (s0 >= 0) ? ONE2 : 0u;
      uint2 u = *(const uint2*)(gc + (size_t)idx * 16 + (f4 << 2));
      p0 = __hfma2(u2h2(u.x), u2h2(mh), p0);
      p1 = __hfma2(u2h2(u.y), u2h2(mh), p1);
    }
    a0 += __low2float(p0); a1 += __high2float(p0);
    a2 += __low2float(p1); a3 += __high2float(p1);
  }
  a0 += __shfl_xor(a0, 4, 64);  a1 += __shfl_xor(a1, 4, 64);
  a2 += __shfl_xor(a2, 4, 64);  a3 += __shfl_xor(a3, 4, 64);
  a0 += __shfl_xor(a0, 8, 64);  a1 += __shfl_xor(a1, 8, 64);
  a2 += __shfl_xor(a2, 8, 64);  a3 += __shfl_xor(a3, 8, 64);
  if (vok && e_slot == 0) {
    float nm = nrm[v];
    float nm2 = nm * nm;
    __half2 w0 = __floats2half2_rn(a0 * nm2, a1 * nm2);
    __half2 w1 = __floats2half2_rn(a2 * nm2, a3 * nm2);
    uint2 st;
    st.x = *reinterpret_cast<uint32_t*>(&w0);
    st.y = *reinterpret_cast<uint32_t*>(&w1);
    *(uint2*)(go + ((size_t)v << 4) + (f4 << 2)) = st;
  }
}

// layer-1 only: g0 = x * nrm (chunked, pads zero)
template<int DIN>
__global__ void init_g0_kernel(const float* __restrict__ x, const float* __restrict__ nrm,
                               __half* __restrict__ g0, int n) {
  constexpr int PD = (DIN + 15) & ~15;
  int lane = threadIdx.x & 63;
  int v = blockIdx.x * 4 + (threadIdx.x >> 6);
  if (v >= n) return;
  float nm = nrm[v];
  for (int f = lane; f < PD; f += 64) {
    float val = (f < DIN) ? x[(size_t)v * DIN + f] * nm : 0.f;
    g0[(((size_t)(f >> 4) * n + v) << 4) + (f & 15)] = __float2half(val);
  }
}

// pad W [5*DIN][DOUT] -> Wp [5*PD][DOUT] (pad rows zero)
__global__ void padw_kernel(const float* __restrict__ W, float* __restrict__ Wp,
                            int din, int dout, int pd) {
  int i = blockIdx.x * 256 + threadIdx.x;
  int total = 5 * pd * dout;
  if (i >= total) return;
  int f = i / dout, j = i - f * dout;
  int hop = f / pd, rem = f - hop * pd;
  Wp[i] = (rem < din) ? W[(size_t)(hop * din + rem) * dout + j] : 0.f;
}

// combine v4: block = 64 nodes, wave wv owns outputs [wv*QO, ...) (wave-uniform
// column offset -> W/bias scalar loads). Cross-wave l2norm via LDS ssq.
template<int DIN, int DOUT, bool LAST>
__global__ __launch_bounds__(256) void combine_kernel(
    const __half* __restrict__ gbase, const float* __restrict__ nrm,
    const float* __restrict__ Wp, const float* __restrict__ bias,
    __half* __restrict__ gnext, float* __restrict__ Xout, int n) {
  constexpr int PD  = (DIN + 15) & ~15;
  constexpr int NCH = PD / 16;
  constexpr int PDN = (DOUT + 15) & ~15;
  constexpr int QO  = ((DOUT + 7) / 8) * 2;   // even, 4*QO >= DOUT
  __shared__ float ssq[4 * 64];
  int lane = threadIdx.x & 63, wv = threadIdx.x >> 6;
  int v = blockIdx.x * 64 + lane;
  bool vok = (v < n);
  int vc = vok ? v : 0;
  const size_t slabh = (size_t)n * 80;
  int cofs = __builtin_amdgcn_readfirstlane(wv) * QO;   // wave-uniform
  float acc[QO];
  #pragma unroll
  for (int jj = 0; jj < QO; ++jj) acc[jj] = 0.f;
  const float* wb = Wp + cofs;
  for (int hop = 0; hop < 5; ++hop) {
    const __half* hrow = gbase + (size_t)hop * slabh + ((size_t)vc << 4);
    #pragma unroll 1
    for (int ch = 0; ch < NCH; ++ch) {
      uint4 u0 = *(const uint4*)hrow;
      uint4 u1 = *(const uint4*)(hrow + 8);
      float h[16];
      {
        float2 p;
        p = cvt_h2(u0.x); h[0] = p.x; h[1] = p.y;
        p = cvt_h2(u0.y); h[2] = p.x; h[3] = p.y;
        p = cvt_h2(u0.z); h[4] = p.x; h[5] = p.y;
        p = cvt_h2(u0.w); h[6] = p.x; h[7] = p.y;
        p = cvt_h2(u1.x); h[8] = p.x; h[9] = p.y;
        p = cvt_h2(u1.y); h[10] = p.x; h[11] = p.y;
        p = cvt_h2(u1.z); h[12] = p.x; h[13] = p.y;
        p = cvt_h2(u1.w); h[14] = p.x; h[15] = p.y;
      }
      #pragma unroll
      for (int s = 0; s < 16; ++s) {
        #pragma unroll
        for (int jj = 0; jj < QO; ++jj) acc[jj] += h[s] * wb[s * DOUT + jj];
      }
      wb += 16 * DOUT;
      hrow += ((size_t)n << 4);
    }
  }
  float rn = 1.f / nrm[vc];
  float ss = 0.f;
  #pragma unroll
  for (int jj = 0; jj < QO; ++jj) {
    int j = cofs + jj;
    float y = (j < DOUT) ? fmaxf(bias[j] + acc[jj] * rn, 0.f) : 0.f;
    acc[jj] = y;
    ss += y * y;
  }
  ssq[wv * 64 + lane] = ss;
  __syncthreads();          // also orders all slab-0 reads before in-place writes
  if (!vok) return;
  float tot = ssq[lane] + ssq[64 + lane] + ssq[128 + lane] + ssq[192 + lane];
  float sc = 1.f / fmaxf(sqrtf(tot), 1e-12f);
  if (LAST) {
    #pragma unroll
    for (int jj = 0; jj < QO; ++jj) {
      int j = cofs + jj;
      if (j < DOUT) Xout[(size_t)v * DOUT + j] = acc[jj] * sc;
    }
  } else {
    float nm = nrm[v];
    #pragma unroll
    for (int jj = 0; jj < QO; jj += 2) {
      int j0 = cofs + jj;
      float a = (j0 < DOUT) ? acc[jj] * sc * nm : 0.f;
      float b = (j0 + 1 < DOUT) ? acc[jj + 1] * sc * nm : 0.f;
      int ch = j0 >> 4, s = j0 & 15;
      *(__half2*)(gnext + (((size_t)ch * n + v) << 4) + s) = __floats2half2_rn(a, b);
    }
    if (wv == 3) {
      #pragma unroll
      for (int j0 = 4 * QO; j0 < PDN; j0 += 2) {    // zero-fill padded tail
        int ch = j0 >> 4, s = j0 & 15;
        *(__half2*)(gnext + (((size_t)ch * n + v) << 4) + s) = __floats2half2_rn(0.f, 0.f);
      }
    }
  }
}

// ---------------- ligand GNN: small-n fused hop (g is L2-resident) --------

template<int DIN, int GS, int DOUT>
__global__ void init_gemm_kernel(const float* __restrict__ x, const float* __restrict__ nrm,
                                 const float* __restrict__ W, const float* __restrict__ bias,
                                 __half* __restrict__ gout, float* __restrict__ y, int n) {
  int lane = threadIdx.x & 63;
  int v = blockIdx.x * 4 + (threadIdx.x >> 6);
  if (v >= n) return;
  float nm = nrm[v];
  const float* xr = x + (size_t)v * DIN;
  float hA = (lane < DIN) ? xr[lane] : 0.f;
  float hB = 0.f;
  if constexpr (DIN > 64) { if (lane + 64 < DIN) hB = xr[lane + 64]; }
  __half* go = gout + (size_t)v * GS;
  if (lane < DIN) go[lane] = __float2half(hA * nm);
  if constexpr (DIN > 64) { if (lane + 64 < DIN) go[lane + 64] = __float2half(hB * nm); }
  int cl = (lane < DOUT) ? lane : 0;
  float acc = bias[cl];
  const float* Wk = W + cl;
  #pragma unroll
  for (int f = 0; f < DIN; ++f) {
    float hf = (f < 64) ? __shfl(hA, f, 64) : __shfl(hB, f - 64, 64);
    acc += hf * Wk[(size_t)f * DOUT];
  }
  if (lane < DOUT) y[(size_t)v * DOUT + lane] = acc;
}

template<int DIN, int GS, int DOUT, bool WRITEG, bool FINAL>
__global__ void fused_hop_kernel(const __half* __restrict__ gin, const int* __restrict__ rp,
                                 const int* __restrict__ col, const float* __restrict__ nrm,
                                 const float* __restrict__ W, __half* __restrict__ gout,
                                 float* __restrict__ y, float* __restrict__ Xout,
                                 int k, int n) {
  int lane = threadIdx.x & 63;
  int v = blockIdx.x * 4 + (threadIdx.x >> 6);
  if (v >= n) return;
  int beg = rp[v], end = rp[v + 1];
  float a0 = 0.f, a1 = 0.f;
  for (int base = beg; base < end; base += 64) {
    int m = end - base; if (m > 64) m = 64;
    int myc = (lane < m) ? col[base + lane] : 0;
    int j = 0;
    for (; j + 8 <= m; j += 8) {
      int ss[8];
      float t0[8], t1[8];
      #pragma unroll
      for (int u = 0; u < 8; ++u) ss[u] = __shfl(myc, j + u, 64);
      #pragma unroll
      for (int u = 0; u < 8; ++u) {
        const __half* rr = gin + (size_t)ss[u] * GS;
        t0[u] = (lane < DIN) ? __half2float(rr[lane]) : 0.f;
        if constexpr (DIN > 64) t1[u] = (lane + 64 < DIN) ? __half2float(rr[lane + 64]) : 0.f;
      }
      #pragma unroll
      for (int u = 0; u < 8; ++u) {
        a0 += t0[u];
        if constexpr (DIN > 64) a1 += t1[u];
      }
    }
    for (; j < m; ++j) {
      int s = __shfl(myc, j, 64);
      const __half* rr = gin + (size_t)s * GS;
      if (lane < DIN) a0 += __half2float(rr[lane]);
      if constexpr (DIN > 64) { if (lane + 64 < DIN) a1 += __half2float(rr[lane + 64]); }
    }
  }
  float nm = nrm[v];
  float hA = a0 * nm, hB = a1 * nm;
  if (WRITEG) {
    __half* go = gout + (size_t)v * GS;
    if (lane < DIN) go[lane] = __float2half(hA * nm);
    if constexpr (DIN > 64) { if (lane + 64 < DIN) go[lane + 64] = __float2half(hB * nm); }
  }
  int cl = (lane < DOUT) ? lane : 0;
  float acc = 0.f;
  if (lane < DOUT) acc = y[(size_t)v * DOUT + lane];
  const float* Wk = W + (size_t)k * DIN * DOUT + cl;
  #pragma unroll
  for (int f = 0; f < DIN; ++f) {
    float hf = (f < 64) ? __shfl(hA, f, 64) : __shfl(hB, f - 64, 64);
    acc += hf * Wk[(size_t)f * DOUT];
  }
  if constexpr (FINAL) {
    float val = (lane < DOUT) ? fmaxf(acc, 0.f) : 0.f;
    float ss2 = val * val;
    #pragma unroll
    for (int off2 = 32; off2 > 0; off2 >>= 1) ss2 += __shfl_xor(ss2, off2, 64);
    float scale = 1.f / fmaxf(sqrtf(ss2), 1e-12f);
    if (lane < DOUT) Xout[(size_t)v * DOUT + lane] = val * scale;
  } else {
    if (lane < DOUT) y[(size_t)v * DOUT + lane] = acc;
  }
}

// hierarchical segment-max (values >= 0 post relu+l2norm; rep zeroed first)
__global__ void segmax_kernel(const float* __restrict__ X, const int* __restrict__ gid,
                              float* __restrict__ rep, int n, int row_off) {
  __shared__ float tab[4][45];
  __shared__ int gids[256];
  int t = threadIdx.x;
  for (int i = t; i < 4 * 45; i += 256) ((float*)tab)[i] = 0.f;
  int v0 = blockIdx.x * 256;
  int vend = v0 + 256; if (vend > n) vend = n;
  int nv = vend - v0;
  if (t < nv) gids[t] = gid[v0 + t];
  __syncthreads();
  int g0 = gids[0];
  int total = nv * 45;
  for (int i = t; i < total; i += 256) {
    int vl = i / 45, j = i - vl * 45;
    float val = X[(size_t)(v0 + vl) * 45 + j];
    int rel = gids[vl] - g0;
    if (rel >= 0 && rel < 4)
      atomicMax((unsigned int*)&tab[rel][j], __float_as_uint(val));
    else
      atomicMax((unsigned int*)&rep[(size_t)(row_off + gids[vl]) * 45 + j], __float_as_uint(val));
  }
  __syncthreads();
  for (int i = t; i < 4 * 45; i += 256) {
    float val = ((float*)tab)[i];
    if (val > 0.f) {
      int rel = i / 45, j = i - rel * 45;
      atomicMax((unsigned int*)&rep[(size_t)(row_off + g0 + rel) * 45 + j], __float_as_uint(val));
    }
  }
}

// ---------------- attention ----------------

__global__ void qkv_kernel(const float* __restrict__ rep, const float* __restrict__ w,
                           const float* __restrict__ b, float* __restrict__ qkv) {
  int i = blockIdx.x;      // 0..129
  int t = threadIdx.x;     // 256
  __shared__ float sr[45];
  if (t < 45) sr[t] = (i < 65) ? rep[(size_t)i * 45 + t] : 0.f;
  __syncthreads();
  if (t < 135) {
    float acc = b[t];
    #pragma unroll 5
    for (int d = 0; d < 45; ++d) acc += sr[d] * w[d * 135 + t];
    qkv[(size_t)i * 135 + t] = acc;
  }
}

__global__ void attn_kernel(const float* __restrict__ qkv, const float* __restrict__ proj_w,
                            const float* __restrict__ proj_b, float* __restrict__ ctx) {
  int i = blockIdx.x;     // query row
  int t = threadIdx.x;    // 256
  __shared__ float q[45];
  __shared__ float p[130];
  __shared__ float red[256];
  __shared__ float ao[45];
  if (t < 45) q[t] = qkv[(size_t)i * 135 + t];
  __syncthreads();
  float s = -1e30f;
  if (t < 130) {
    int j = t;
    float dot = 0.f;
    #pragma unroll 5
    for (int d = 0; d < 45; ++d) dot += q[d] * qkv[(size_t)j * 135 + 45 + d];
    dot *= 0.14907119849998599f;  // 45^-0.5
    bool mz;  // mask == 0 ?
    if (i == 64 && j == 64) mz = true;
    else if (i == 64 || j == 64) mz = false;
    else mz = !(i == j && i < 65);
    s = mz ? -1e9f : dot;
  }
  red[t] = s;
  __syncthreads();
  #pragma unroll
  for (int off = 128; off > 0; off >>= 1) {
    if (t < off) red[t] = fmaxf(red[t], red[t + off]);
    __syncthreads();
  }
  float mx = red[0];
  __syncthreads();
  float e = (t < 130) ? expf(s - mx) : 0.f;
  red[t] = e;
  __syncthreads();
  #pragma unroll
  for (int off = 128; off > 0; off >>= 1) {
    if (t < off) red[t] += red[t + off];
    __syncthreads();
  }
  float denom = red[0];
  __syncthreads();
  if (t < 130) p[t] = e / denom;
  __syncthreads();
  if (t < 45) {
    float acc = 0.f;
    for (int j = 0; j < 130; ++j) acc += p[j] * qkv[(size_t)j * 135 + 90 + t];
    ao[t] = acc;
  }
  __syncthreads();
  if (t < 45) {
    float pr = proj_b[t];
    #pragma unroll 5
    for (int e2 = 0; e2 < 45; ++e2) pr += ao[e2] * proj_w[e2 * 45 + t];
    ctx[(size_t)i * 45 + t] = pr;
  }
}

// ---------------- head MLP ----------------

__global__ void bias_init_kernel(const float* __restrict__ b, float* __restrict__ out, int n) {
  int i = blockIdx.x * 256 + threadIdx.x;
  if (i < n) out[i] = b[i];
}

template<bool RELU_IN>
__global__ void fc_splitk_kernel(const float* __restrict__ x, const float* __restrict__ W,
                                 float* __restrict__ out, int nin, int nout, int kchunk) {
  __shared__ float xs[1024];
  int k0 = blockIdx.y * kchunk;
  int k1 = k0 + kchunk; if (k1 > nin) k1 = nin;
  int len = k1 - k0;
  for (int i = threadIdx.x; i < len; i += blockDim.x) {
    float v = x[k0 + i];
    xs[i] = RELU_IN ? fmaxf(v, 0.f) : v;
  }
  __syncthreads();
  int j = blockIdx.x * blockDim.x + threadIdx.x;
  if (j < nout) {
    float acc = 0.f;
    const float* Wp = W + (size_t)k0 * nout + j;
    for (int i = 0; i < len; ++i) acc += xs[i] * Wp[(size_t)i * nout];
    atomicAdd(&out[j], acc);
  }
}

__global__ void final_fc_kernel(const float* __restrict__ x, const float* __restrict__ W,
                                const float* __restrict__ b, float* __restrict__ out) {
  __shared__ float red[512];
  int t = threadIdx.x;
  float acc = 0.f;
  if (t < 500) acc = fmaxf(x[t], 0.f) * W[t];
  red[t] = acc;
  __syncthreads();
  #pragma unroll
  for (int off = 256; off > 0; off >>= 1) {
    if (t < off) red[t] += red[t + off];
    __syncthreads();
  }
  if (t == 0) {
    float z = red[0] + b[0];
    out[0] = 1.f / (1.f + expf(-z));
  }
}

// ---------------- host-side orchestration ----------------

struct Bufs {
  __half* slabs;         // protein: 5 slabs of n*80 halves
  __half *ligA, *ligB;   // ligand ping/pong
  float *X, *Y, *nrm, *Wp;
  int *cnt, *cur, *rp, *col, *bsum, *gcur;
  uint2* ebuf;           // aliases slabs (only live during build_csr)
};

template<int DIN, int DOUT, bool LAST>
void run_layer_prot(const Bufs& g, const float* W, const float* b, int n, hipStream_t st) {
  constexpr int PD = (DIN + 15) & ~15;
  constexpr int NPASS = PD / 16;
  int nbn = (n + 15) / 16;
  size_t slabh = (size_t)n * 80;
  for (int k = 1; k <= 4; ++k)
    gather_all_kernel<<<NPASS * nbn, 256, 0, st>>>(g.slabs + (size_t)(k - 1) * slabh,
                                                   g.rp, g.col, g.nrm,
                                                   g.slabs + (size_t)k * slabh, n, nbn);
  int wtotal = 5 * PD * DOUT;
  padw_kernel<<<(wtotal + 255) / 256, 256, 0, st>>>(W, g.Wp, DIN, DOUT, PD);
  combine_kernel<DIN, DOUT, LAST><<<(n + 63) / 64, 256, 0, st>>>(
      g.slabs, g.nrm, g.Wp, b, g.slabs, g.X, n);
}

template<int DIN, int GS, int DOUT>
void run_layer_lig(const float* xin, const Bufs& g, const float* W, const float* b,
                   int n, hipStream_t st) {
  int nb = (n + 3) / 4;
  init_gemm_kernel<DIN, GS, DOUT><<<nb, 256, 0, st>>>(xin, g.nrm, W, b, g.ligA, g.Y, n);
  const __half* gin = g.ligA;
  __half* gout = g.ligB;
  for (int k = 1; k <= 4; ++k) {
    if (k < 4)
      fused_hop_kernel<DIN, GS, DOUT, true, false><<<nb, 256, 0, st>>>(gin, g.rp, g.col, g.nrm, W, gout, g.Y, g.X, k, n);
    else
      fused_hop_kernel<DIN, GS, DOUT, false, true><<<nb, 256, 0, st>>>(gin, g.rp, g.col, g.nrm, W, gout, g.Y, g.X, 4, n);
    __half* t = (__half*)gin; gin = gout; gout = t;
  }
}

void build_csr(const int* src, const int* dst, const Bufs& g, int n, int e, hipStream_t st) {
  hipMemsetAsync(g.cnt, 0, (size_t)n * 4, st);
  hipMemsetAsync(g.cur, 0, (size_t)n * 4, st);
  hist_kernel<<<(e + 255) / 256, 256, 0, st>>>(dst, g.cnt, e);
  int nb1 = (n + 1023) / 1024;
  scan1_kernel<<<nb1, 256, 0, st>>>(g.cnt, g.rp, g.bsum, g.nrm, n);
  scan2_kernel<<<1, 256, 0, st>>>(g.bsum, nb1, g.rp + n);
  scan3_kernel<<<(n + 255) / 256, 256, 0, st>>>(g.rp, g.bsum, n);
  // bucketed two-pass scatter (col writes stay in L2-resident windows)
  gcur_init_kernel<<<1, 64, 0, st>>>(g.rp, g.gcur, n);
  scat1_kernel<<<(e + 4095) / 4096, 256, 0, st>>>(src, dst, g.gcur, g.ebuf, e);
  scat2_kernel<<<(e + 255) / 256, 256, 0, st>>>(g.ebuf, g.rp, g.cur, g.col, e);
}

} // namespace

extern "C" void kernel_launch(void* const* d_in, const int* in_sizes, int n_in,
                              void* d_out, int out_size, void* d_ws, size_t ws_size,
                              hipStream_t stream) {
  (void)in_sizes; (void)n_in; (void)out_size;

  const float* prot_x = (const float*)d_in[0];
  const float* lig_x  = (const float*)d_in[1];
  const float* pW[3] = {(const float*)d_in[2], (const float*)d_in[4], (const float*)d_in[6]};
  const float* pB[3] = {(const float*)d_in[3], (const float*)d_in[5], (const float*)d_in[7]};
  const float* lW[4] = {(const float*)d_in[8], (const float*)d_in[10], (const float*)d_in[12], (const float*)d_in[14]};
  const float* lB[4] = {(const float*)d_in[9], (const float*)d_in[11], (const float*)d_in[13], (const float*)d_in[15]};
  const float* qkv_w = (const float*)d_in[16];
  const float* qkv_b = (const float*)d_in[17];
  const float* proj_w = (const float*)d_in[18];
  const float* proj_b = (const float*)d_in[19];
  const float* h0_w = (const float*)d_in[20];
  const float* h0_b = (const float*)d_in[21];
  const float* h1_w = (const float*)d_in[22];
  const float* h1_b = (const float*)d_in[23];
  const float* h2_w = (const float*)d_in[24];
  const float* h2_b = (const float*)d_in[25];
  const float* fc_w = (const float*)d_in[26];
  const float* fc_b = (const float*)d_in[27];
  const int* prot_src = (const int*)d_in[28];
  const int* prot_dst = (const int*)d_in[29];
  const int* prot_gid = (const int*)d_in[30];
  const int* lig_src  = (const int*)d_in[31];
  const int* lig_dst  = (const int*)d_in[32];
  const int* lig_gid  = (const int*)d_in[33];

  // workspace carve-up
  char* w = (char*)d_ws;
  size_t off = 0;
  auto alloc = [&](size_t bytes) -> void* {
    void* p = w + off;
    off += (bytes + 255) & ~(size_t)255;
    return p;
  };
  __half* slabs = (__half*)alloc((size_t)5 * NPROT * 80 * 2);   // 80 MB: g0..g4
  __half* ligA  = (__half*)alloc((size_t)NLIG * 96 * 2);
  __half* ligB  = (__half*)alloc((size_t)NLIG * 96 * 2);
  float* X   = (float*)alloc((size_t)NPROT * 45 * 4);
  float* Y   = (float*)alloc((size_t)NLIG * 50 * 4);
  float* nrm = (float*)alloc((size_t)NPROT * 4);
  float* Wp  = (float*)alloc((size_t)5 * 80 * 50 * 4 + 256);  // + scalar-OOB pad
  int* cnt   = (int*)alloc((size_t)NPROT * 4);
  int* cur   = (int*)alloc((size_t)NPROT * 4);
  int* rp    = (int*)alloc(((size_t)NPROT + 1) * 4);
  int* colb  = (int*)alloc((size_t)EPROT * 4);
  int* bsum  = (int*)alloc((size_t)256 * 4);
  int* gcur  = (int*)alloc((size_t)64 * 4);
  float* rep = (float*)alloc((size_t)65 * 45 * 4);
  float* qkvb = (float*)alloc((size_t)130 * 135 * 4);
  float* ctx  = (float*)alloc((size_t)5850 * 4);
  float* hb0  = (float*)alloc((size_t)2000 * 4);
  float* hb1  = (float*)alloc((size_t)1000 * 4);
  float* hb2  = (float*)alloc((size_t)500 * 4);
  if (off > ws_size) return;  // workspace too small: fail loudly via validation

  hipMemsetAsync(rep, 0, (size_t)65 * 45 * 4, stream);

  Bufs g{slabs, ligA, ligB, X, Y, nrm, Wp, cnt, cur, rp, colb, bsum, gcur,
         (uint2*)slabs /*ebuf aliases slabs*/};

  // ---- protein GNN (chunked L2-resident gathers + wave-split combine) ----
  build_csr(prot_src, prot_dst, g, NPROT, EPROT, stream);   // ebuf uses slabs (dead here)
  init_g0_kernel<74><<<(NPROT + 3) / 4, 256, 0, stream>>>(prot_x, g.nrm, g.slabs, NPROT);
  run_layer_prot<74, 50, false>(g, pW[0], pB[0], NPROT, stream);
  run_layer_prot<50, 45, false>(g, pW[1], pB[1], NPROT, stream);
  run_layer_prot<45, 45, true >(g, pW[2], pB[2], NPROT, stream);
  segmax_kernel<<<(NPROT + 255) / 256, 256, 0, stream>>>(g.X, prot_gid, rep, NPROT, 1);

  // ---- ligand GNN (small; fused path; slabs dead again -> ebuf reuse ok) ----
  build_csr(lig_src, lig_dst, g, NLIG, ELIG, stream);
  run_layer_lig<74, 96, 50>(lig_x, g, lW[0], lB[0], NLIG, stream);
  run_layer_lig<50, 64, 45>(g.X, g, lW[1], lB[1], NLIG, stream);
  run_layer_lig<45, 64, 45>(g.X, g, lW[2], lB[2], NLIG, stream);
  run_layer_lig<45, 64, 45>(g.X, g, lW[3], lB[3], NLIG, stream);
  segmax_kernel<<<(NLIG + 255) / 256, 256, 0, stream>>>(g.X, lig_gid, rep, NLIG, 0);

  // ---- attention ----
  qkv_kernel<<<130, 256, 0, stream>>>(rep, qkv_w, qkv_b, qkvb);
  attn_kernel<<<130, 256, 0, stream>>>(qkvb, proj_w, proj_b, ctx);

  // ---- head MLP ----
  bias_init_kernel<<<8, 256, 0, stream>>>(h0_b, hb0, 2000);
  fc_splitk_kernel<false><<<dim3(8, 8), 256, 0, stream>>>(ctx, h0_w, hb0, 5850, 2000, 732);
  bias_init_kernel<<<4, 256, 0, stream>>>(h1_b, hb1, 1000);
  fc_splitk_kernel<true><<<dim3(4, 4), 256, 0, stream>>>(hb0, h1_w, hb1, 2000, 1000, 500);
  bias_init_kernel<<<2, 256, 0, stream>>>(h2_b, hb2, 500);
  fc_splitk_kernel<true><<<dim3(2, 2), 256, 0, stream>>>(hb1, h2_w, hb2, 1000, 500, 500);
  final_fc_kernel<<<1, 512, 0, stream>>>(hb2, fc_w, fc_b, (float*)d_out);
}

// Round 13
// 1303.566 us; speedup vs baseline: 1.6384x; 1.1360x over previous
//
#include <hip/hip_runtime.h>
#include <hip/hip_fp16.h>
#include <cstddef>
#include <cstdint>

namespace {

constexpr int NPROT = 100000;
constexpr int EPROT = 1600000;
constexpr int NLIG  = 5000;
constexpr int ELIG  = 80000;

// ---------------- CSR construction ----------------

__global__ void hist_kernel(const int* __restrict__ dst, int* __restrict__ cnt, int e) {
  int i = blockIdx.x * 256 + threadIdx.x;
  if (i < e) atomicAdd(&cnt[dst[i]], 1);
}

// per-block (1024 elems) exclusive scan; also computes nrm = max(deg,1)^-0.5
__global__ void scan1_kernel(const int* __restrict__ cnt, int* __restrict__ rp,
                             int* __restrict__ bsum, float* __restrict__ nrm, int n) {
  __shared__ int wsum[4];
  int t = threadIdx.x;
  int base = blockIdx.x * 1024 + t * 4;
  int v0 = 0, v1 = 0, v2 = 0, v3 = 0;
  if (base + 3 < n) {
    int4 val = *(const int4*)(cnt + base);
    v0 = val.x; v1 = val.y; v2 = val.z; v3 = val.w;
  } else if (base < n) {
    v0 = cnt[base];
    if (base + 1 < n) v1 = cnt[base + 1];
    if (base + 2 < n) v2 = cnt[base + 2];
  }
  if (base < n)     nrm[base]     = 1.0f / sqrtf(fmaxf((float)v0, 1.0f));
  if (base + 1 < n) nrm[base + 1] = 1.0f / sqrtf(fmaxf((float)v1, 1.0f));
  if (base + 2 < n) nrm[base + 2] = 1.0f / sqrtf(fmaxf((float)v2, 1.0f));
  if (base + 3 < n) nrm[base + 3] = 1.0f / sqrtf(fmaxf((float)v3, 1.0f));
  int ts = v0 + v1 + v2 + v3;
  int lane = t & 63, wv = t >> 6;
  int incl = ts;
  #pragma unroll
  for (int off = 1; off < 64; off <<= 1) {
    int o = __shfl_up(incl, off, 64);
    if (lane >= off) incl += o;
  }
  if (lane == 63) wsum[wv] = incl;
  __syncthreads();
  int woff = 0;
  #pragma unroll
  for (int i = 0; i < 4; ++i) if (i < wv) woff += wsum[i];
  int excl = woff + incl - ts;
  int o0 = excl, o1 = o0 + v0, o2 = o1 + v1, o3 = o2 + v2;
  if (base + 3 < n) {
    *(int4*)(rp + base) = make_int4(o0, o1, o2, o3);
  } else if (base < n) {
    rp[base] = o0;
    if (base + 1 < n) rp[base + 1] = o1;
    if (base + 2 < n) rp[base + 2] = o2;
  }
  if (t == 255) bsum[blockIdx.x] = woff + incl;  // block total
}

// exclusive scan of <=256 block sums; writes grand total to rp[n]
__global__ void scan2_kernel(int* __restrict__ bsum, int nb, int* __restrict__ rp_end) {
  __shared__ int s[256];
  int t = threadIdx.x;
  int v = (t < nb) ? bsum[t] : 0;
  s[t] = v;
  __syncthreads();
  int val = v;
  for (int off = 1; off < 256; off <<= 1) {
    int add = (t >= off) ? s[t - off] : 0;
    __syncthreads();
    val += add;
    s[t] = val;
    __syncthreads();
  }
  if (t < nb) bsum[t] = val - v;  // exclusive
  if (t == 255) *rp_end = val;    // total
}

__global__ void scan3_kernel(int* __restrict__ rp, const int* __restrict__ bsum, int n) {
  int i = blockIdx.x * 256 + threadIdx.x;
  if (i < n) rp[i] += bsum[i >> 10];
}

// ---- bucketed two-pass edge scatter (bucket = dst>>11, col window L2-resident)

__global__ void gcur_init_kernel(const int* __restrict__ rp, int* __restrict__ gcur, int n) {
  int t = threadIdx.x;  // 1 block, 64 threads
  if (t < 64) gcur[t] = rp[min(t << 11, n)];
}

__global__ void scat1_kernel(const int* __restrict__ src, const int* __restrict__ dst,
                             int* __restrict__ gcur, uint2* __restrict__ ebuf, int e) {
  __shared__ int lh[64], lb[64];
  int t = threadIdx.x;
  if (t < 64) lh[t] = 0;
  __syncthreads();
  int base = blockIdx.x * 4096;
  int d[16], rk[16];
  #pragma unroll
  for (int j = 0; j < 16; ++j) {
    int i = base + j * 256 + t;
    if (i < e) {
      d[j] = dst[i];
      rk[j] = atomicAdd(&lh[min(d[j] >> 11, 63)], 1);
    }
  }
  __syncthreads();
  if (t < 64 && lh[t] > 0) lb[t] = atomicAdd(&gcur[t], lh[t]);
  __syncthreads();
  #pragma unroll
  for (int j = 0; j < 16; ++j) {
    int i = base + j * 256 + t;
    if (i < e)
      ebuf[lb[min(d[j] >> 11, 63)] + rk[j]] = make_uint2((unsigned)src[i], (unsigned)d[j]);
  }
}

__global__ void scat2_kernel(const uint2* __restrict__ ebuf, const int* __restrict__ rp,
                             int* __restrict__ cur, int* __restrict__ col, int e) {
  int i = blockIdx.x * 256 + threadIdx.x;
  if (i < e) {
    uint2 p = ebuf[i];
    int d = (int)p.y;
    int q = rp[d] + atomicAdd(&cur[d], 1);
    col[q] = (int)p.x;
  }
}

// ---------------- protein GNN ----------------
// g_k = nrm.*h_k stored fp16 in 16-feat chunks, padded width PD=ceil(DIN/16)*16
// (pads stay zero). Slab k (hop k) at gbase + k*slabh, slabh = n*80 halves.
// Chunk c, node v, slot s: addr = (c*n + v)*16 + s  (32B rows, L2-friendly).
// gathers: g_k = nrm^2 * sum_{src} g_{k-1}[src], one L2-resident chunk/pass.
// combine: block = 64 nodes; 4 waves each own a wave-uniform quarter of DOUT
// (W via scalar loads); cross-wave l2norm via LDS; writes next g0 in-place.

__device__ __forceinline__ float2 cvt_h2(uint32_t u) {
  __half2 h = *reinterpret_cast<__half2*>(&u);
  return make_float2(__low2float(h), __high2float(h));
}

// grid = NPASS*nbn (pass-major); 256 thr = 4 waves; wave = 4 nodes x 16 lanes
// (4 edge slots x 4 f4-lanes, 8B loads); 4 clamped branch-free loads in flight.
__global__ void gather_all_kernel(const __half* __restrict__ gin, const int* __restrict__ rp,
                                  const int* __restrict__ col, const float* __restrict__ nrm,
                                  __half* __restrict__ gout, int n, int nbn) {
  int pass = blockIdx.x / nbn;
  int bid = blockIdx.x - pass * nbn;
  int lane = threadIdx.x & 63, wv = threadIdx.x >> 6;
  int q = lane >> 4, r = lane & 15;
  int e_slot = r >> 2, f4 = r & 3;
  int v = bid * 16 + wv * 4 + q;
  bool vok = (v < n);
  int beg = 0, deg = 0;
  if (vok) { beg = rp[v]; deg = rp[v + 1] - beg; }
  const __half* gc = gin + (size_t)pass * n * 16;
  __half* go = gout + (size_t)pass * n * 16;
  float a0 = 0.f, a1 = 0.f, a2 = 0.f, a3 = 0.f;
  for (int base = 0; __any(base < deg); base += 16) {
    int ec = (base + r < deg) ? col[beg + base + r] : -1;
    #pragma unroll
    for (int js = 0; js < 16; js += 4) {
      int sl = (q << 4) + js + e_slot;
      int s0 = __shfl(ec, sl, 64);
      int idx = (s0 >= 0) ? s0 : 0;             // clamped: row 0 when invalid
      float m = (s0 >= 0) ? 1.f : 0.f;
      uint2 u = *(const uint2*)(gc + (size_t)idx * 16 + (f4 << 2));
      float2 p0 = cvt_h2(u.x), p1 = cvt_h2(u.y);
      a0 = fmaf(m, p0.x, a0); a1 = fmaf(m, p0.y, a1);
      a2 = fmaf(m, p1.x, a2); a3 = fmaf(m, p1.y, a3);
    }
  }
  a0 += __shfl_xor(a0, 4, 64);  a1 += __shfl_xor(a1, 4, 64);
  a2 += __shfl_xor(a2, 4, 64);  a3 += __shfl_xor(a3, 4, 64);
  a0 += __shfl_xor(a0, 8, 64);  a1 += __shfl_xor(a1, 8, 64);
  a2 += __shfl_xor(a2, 8, 64);  a3 += __shfl_xor(a3, 8, 64);
  if (vok && e_slot == 0) {
    float nm = nrm[v];
    float nm2 = nm * nm;
    __half2 w0 = __floats2half2_rn(a0 * nm2, a1 * nm2);
    __half2 w1 = __floats2half2_rn(a2 * nm2, a3 * nm2);
    uint2 st;
    st.x = *reinterpret_cast<uint32_t*>(&w0);
    st.y = *reinterpret_cast<uint32_t*>(&w1);
    *(uint2*)(go + ((size_t)v << 4) + (f4 << 2)) = st;
  }
}

// layer-1 only: g0 = x * nrm (chunked, pads zero)
template<int DIN>
__global__ void init_g0_kernel(const float* __restrict__ x, const float* __restrict__ nrm,
                               __half* __restrict__ g0, int n) {
  constexpr int PD = (DIN + 15) & ~15;
  int lane = threadIdx.x & 63;
  int v = blockIdx.x * 4 + (threadIdx.x >> 6);
  if (v >= n) return;
  float nm = nrm[v];
  for (int f = lane; f < PD; f += 64) {
    float val = (f < DIN) ? x[(size_t)v * DIN + f] * nm : 0.f;
    g0[(((size_t)(f >> 4) * n + v) << 4) + (f & 15)] = __float2half(val);
  }
}

// pad W [5*DIN][DOUT] -> Wp [5*PD][DOUT] (pad rows zero)
__global__ void padw_kernel(const float* __restrict__ W, float* __restrict__ Wp,
                            int din, int dout, int pd) {
  int i = blockIdx.x * 256 + threadIdx.x;
  int total = 5 * pd * dout;
  if (i >= total) return;
  int f = i / dout, j = i - f * dout;
  int hop = f / pd, rem = f - hop * pd;
  Wp[i] = (rem < din) ? W[(size_t)(hop * din + rem) * dout + j] : 0.f;
}

// combine v4: block = 64 nodes, wave wv owns outputs [wv*QO, ...) (wave-uniform
// column offset -> W/bias scalar loads). Cross-wave l2norm via LDS ssq.
template<int DIN, int DOUT, bool LAST>
__global__ __launch_bounds__(256) void combine_kernel(
    const __half* __restrict__ gbase, const float* __restrict__ nrm,
    const float* __restrict__ Wp, const float* __restrict__ bias,
    __half* __restrict__ gnext, float* __restrict__ Xout, int n) {
  constexpr int PD  = (DIN + 15) & ~15;
  constexpr int NCH = PD / 16;
  constexpr int PDN = (DOUT + 15) & ~15;
  constexpr int QO  = ((DOUT + 7) / 8) * 2;   // even, 4*QO >= DOUT
  __shared__ float ssq[4 * 64];
  int lane = threadIdx.x & 63, wv = threadIdx.x >> 6;
  int v = blockIdx.x * 64 + lane;
  bool vok = (v < n);
  int vc = vok ? v : 0;
  const size_t slabh = (size_t)n * 80;
  int cofs = __builtin_amdgcn_readfirstlane(wv) * QO;   // wave-uniform
  float acc[QO];
  #pragma unroll
  for (int jj = 0; jj < QO; ++jj) acc[jj] = 0.f;
  const float* wb = Wp + cofs;
  for (int hop = 0; hop < 5; ++hop) {
    const __half* hrow = gbase + (size_t)hop * slabh + ((size_t)vc << 4);
    #pragma unroll 1
    for (int ch = 0; ch < NCH; ++ch) {
      uint4 u0 = *(const uint4*)hrow;
      uint4 u1 = *(const uint4*)(hrow + 8);
      float h[16];
      {
        float2 p;
        p = cvt_h2(u0.x); h[0] = p.x; h[1] = p.y;
        p = cvt_h2(u0.y); h[2] = p.x; h[3] = p.y;
        p = cvt_h2(u0.z); h[4] = p.x; h[5] = p.y;
        p = cvt_h2(u0.w); h[6] = p.x; h[7] = p.y;
        p = cvt_h2(u1.x); h[8] = p.x; h[9] = p.y;
        p = cvt_h2(u1.y); h[10] = p.x; h[11] = p.y;
        p = cvt_h2(u1.z); h[12] = p.x; h[13] = p.y;
        p = cvt_h2(u1.w); h[14] = p.x; h[15] = p.y;
      }
      #pragma unroll
      for (int s = 0; s < 16; ++s) {
        #pragma unroll
        for (int jj = 0; jj < QO; ++jj) acc[jj] += h[s] * wb[s * DOUT + jj];
      }
      wb += 16 * DOUT;
      hrow += ((size_t)n << 4);
    }
  }
  float rn = 1.f / nrm[vc];
  float ss = 0.f;
  #pragma unroll
  for (int jj = 0; jj < QO; ++jj) {
    int j = cofs + jj;
    float y = (j < DOUT) ? fmaxf(bias[j] + acc[jj] * rn, 0.f) : 0.f;
    acc[jj] = y;
    ss += y * y;
  }
  ssq[wv * 64 + lane] = ss;
  __syncthreads();          // also orders all slab-0 reads before in-place writes
  if (!vok) return;
  float tot = ssq[lane] + ssq[64 + lane] + ssq[128 + lane] + ssq[192 + lane];
  float sc = 1.f / fmaxf(sqrtf(tot), 1e-12f);
  if (LAST) {
    #pragma unroll
    for (int jj = 0; jj < QO; ++jj) {
      int j = cofs + jj;
      if (j < DOUT) Xout[(size_t)v * DOUT + j] = acc[jj] * sc;
    }
  } else {
    float nm = nrm[v];
    #pragma unroll
    for (int jj = 0; jj < QO; jj += 2) {
      int j0 = cofs + jj;
      float a = (j0 < DOUT) ? acc[jj] * sc * nm : 0.f;
      float b = (j0 + 1 < DOUT) ? acc[jj + 1] * sc * nm : 0.f;
      int ch = j0 >> 4, s = j0 & 15;
      *(__half2*)(gnext + (((size_t)ch * n + v) << 4) + s) = __floats2half2_rn(a, b);
    }
    if (wv == 3) {
      #pragma unroll
      for (int j0 = 4 * QO; j0 < PDN; j0 += 2) {    // zero-fill padded tail
        int ch = j0 >> 4, s = j0 & 15;
        *(__half2*)(gnext + (((size_t)ch * n + v) << 4) + s) = __floats2half2_rn(0.f, 0.f);
      }
    }
  }
}

// ---------------- ligand GNN: small-n fused hop (g is L2-resident) --------

template<int DIN, int GS, int DOUT>
__global__ void init_gemm_kernel(const float* __restrict__ x, const float* __restrict__ nrm,
                                 const float* __restrict__ W, const float* __restrict__ bias,
                                 __half* __restrict__ gout, float* __restrict__ y, int n) {
  int lane = threadIdx.x & 63;
  int v = blockIdx.x * 4 + (threadIdx.x >> 6);
  if (v >= n) return;
  float nm = nrm[v];
  const float* xr = x + (size_t)v * DIN;
  float hA = (lane < DIN) ? xr[lane] : 0.f;
  float hB = 0.f;
  if constexpr (DIN > 64) { if (lane + 64 < DIN) hB = xr[lane + 64]; }
  __half* go = gout + (size_t)v * GS;
  if (lane < DIN) go[lane] = __float2half(hA * nm);
  if constexpr (DIN > 64) { if (lane + 64 < DIN) go[lane + 64] = __float2half(hB * nm); }
  int cl = (lane < DOUT) ? lane : 0;
  float acc = bias[cl];
  const float* Wk = W + cl;
  #pragma unroll
  for (int f = 0; f < DIN; ++f) {
    float hf = (f < 64) ? __shfl(hA, f, 64) : __shfl(hB, f - 64, 64);
    acc += hf * Wk[(size_t)f * DOUT];
  }
  if (lane < DOUT) y[(size_t)v * DOUT + lane] = acc;
}

template<int DIN, int GS, int DOUT, bool WRITEG, bool FINAL>
__global__ void fused_hop_kernel(const __half* __restrict__ gin, const int* __restrict__ rp,
                                 const int* __restrict__ col, const float* __restrict__ nrm,
                                 const float* __restrict__ W, __half* __restrict__ gout,
                                 float* __restrict__ y, float* __restrict__ Xout,
                                 int k, int n) {
  int lane = threadIdx.x & 63;
  int v = blockIdx.x * 4 + (threadIdx.x >> 6);
  if (v >= n) return;
  int beg = rp[v], end = rp[v + 1];
  float a0 = 0.f, a1 = 0.f;
  for (int base = beg; base < end; base += 64) {
    int m = end - base; if (m > 64) m = 64;
    int myc = (lane < m) ? col[base + lane] : 0;
    int j = 0;
    for (; j + 8 <= m; j += 8) {
      int ss[8];
      float t0[8], t1[8];
      #pragma unroll
      for (int u = 0; u < 8; ++u) ss[u] = __shfl(myc, j + u, 64);
      #pragma unroll
      for (int u = 0; u < 8; ++u) {
        const __half* rr = gin + (size_t)ss[u] * GS;
        t0[u] = (lane < DIN) ? __half2float(rr[lane]) : 0.f;
        if constexpr (DIN > 64) t1[u] = (lane + 64 < DIN) ? __half2float(rr[lane + 64]) : 0.f;
      }
      #pragma unroll
      for (int u = 0; u < 8; ++u) {
        a0 += t0[u];
        if constexpr (DIN > 64) a1 += t1[u];
      }
    }
    for (; j < m; ++j) {
      int s = __shfl(myc, j, 64);
      const __half* rr = gin + (size_t)s * GS;
      if (lane < DIN) a0 += __half2float(rr[lane]);
      if constexpr (DIN > 64) { if (lane + 64 < DIN) a1 += __half2float(rr[lane + 64]); }
    }
  }
  float nm = nrm[v];
  float hA = a0 * nm, hB = a1 * nm;
  if (WRITEG) {
    __half* go = gout + (size_t)v * GS;
    if (lane < DIN) go[lane] = __float2half(hA * nm);
    if constexpr (DIN > 64) { if (lane + 64 < DIN) go[lane + 64] = __float2half(hB * nm); }
  }
  int cl = (lane < DOUT) ? lane : 0;
  float acc = 0.f;
  if (lane < DOUT) acc = y[(size_t)v * DOUT + lane];
  const float* Wk = W + (size_t)k * DIN * DOUT + cl;
  #pragma unroll
  for (int f = 0; f < DIN; ++f) {
    float hf = (f < 64) ? __shfl(hA, f, 64) : __shfl(hB, f - 64, 64);
    acc += hf * Wk[(size_t)f * DOUT];
  }
  if constexpr (FINAL) {
    float val = (lane < DOUT) ? fmaxf(acc, 0.f) : 0.f;
    float ss2 = val * val;
    #pragma unroll
    for (int off2 = 32; off2 > 0; off2 >>= 1) ss2 += __shfl_xor(ss2, off2, 64);
    float scale = 1.f / fmaxf(sqrtf(ss2), 1e-12f);
    if (lane < DOUT) Xout[(size_t)v * DOUT + lane] = val * scale;
  } else {
    if (lane < DOUT) y[(size_t)v * DOUT + lane] = acc;
  }
}

// hierarchical segment-max (values >= 0 post relu+l2norm; rep zeroed first)
__global__ void segmax_kernel(const float* __restrict__ X, const int* __restrict__ gid,
                              float* __restrict__ rep, int n, int row_off) {
  __shared__ float tab[4][45];
  __shared__ int gids[256];
  int t = threadIdx.x;
  for (int i = t; i < 4 * 45; i += 256) ((float*)tab)[i] = 0.f;
  int v0 = blockIdx.x * 256;
  int vend = v0 + 256; if (vend > n) vend = n;
  int nv = vend - v0;
  if (t < nv) gids[t] = gid[v0 + t];
  __syncthreads();
  int g0 = gids[0];
  int total = nv * 45;
  for (int i = t; i < total; i += 256) {
    int vl = i / 45, j = i - vl * 45;
    float val = X[(size_t)(v0 + vl) * 45 + j];
    int rel = gids[vl] - g0;
    if (rel >= 0 && rel < 4)
      atomicMax((unsigned int*)&tab[rel][j], __float_as_uint(val));
    else
      atomicMax((unsigned int*)&rep[(size_t)(row_off + gids[vl]) * 45 + j], __float_as_uint(val));
  }
  __syncthreads();
  for (int i = t; i < 4 * 45; i += 256) {
    float val = ((float*)tab)[i];
    if (val > 0.f) {
      int rel = i / 45, j = i - rel * 45;
      atomicMax((unsigned int*)&rep[(size_t)(row_off + g0 + rel) * 45 + j], __float_as_uint(val));
    }
  }
}

// ---------------- attention ----------------

__global__ void qkv_kernel(const float* __restrict__ rep, const float* __restrict__ w,
                           const float* __restrict__ b, float* __restrict__ qkv) {
  int i = blockIdx.x;      // 0..129
  int t = threadIdx.x;     // 256
  __shared__ float sr[45];
  if (t < 45) sr[t] = (i < 65) ? rep[(size_t)i * 45 + t] : 0.f;
  __syncthreads();
  if (t < 135) {
    float acc = b[t];
    #pragma unroll 5
    for (int d = 0; d < 45; ++d) acc += sr[d] * w[d * 135 + t];
    qkv[(size_t)i * 135 + t] = acc;
  }
}

__global__ void attn_kernel(const float* __restrict__ qkv, const float* __restrict__ proj_w,
                            const float* __restrict__ proj_b, float* __restrict__ ctx) {
  int i = blockIdx.x;     // query row
  int t = threadIdx.x;    // 256
  __shared__ float q[45];
  __shared__ float p[130];
  __shared__ float red[256];
  __shared__ float ao[45];
  if (t < 45) q[t] = qkv[(size_t)i * 135 + t];
  __syncthreads();
  float s = -1e30f;
  if (t < 130) {
    int j = t;
    float dot = 0.f;
    #pragma unroll 5
    for (int d = 0; d < 45; ++d) dot += q[d] * qkv[(size_t)j * 135 + 45 + d];
    dot *= 0.14907119849998599f;  // 45^-0.5
    bool mz;  // mask == 0 ?
    if (i == 64 && j == 64) mz = true;
    else if (i == 64 || j == 64) mz = false;
    else mz = !(i == j && i < 65);
    s = mz ? -1e9f : dot;
  }
  red[t] = s;
  __syncthreads();
  #pragma unroll
  for (int off = 128; off > 0; off >>= 1) {
    if (t < off) red[t] = fmaxf(red[t], red[t + off]);
    __syncthreads();
  }
  float mx = red[0];
  __syncthreads();
  float e = (t < 130) ? expf(s - mx) : 0.f;
  red[t] = e;
  __syncthreads();
  #pragma unroll
  for (int off = 128; off > 0; off >>= 1) {
    if (t < off) red[t] += red[t + off];
    __syncthreads();
  }
  float denom = red[0];
  __syncthreads();
  if (t < 130) p[t] = e / denom;
  __syncthreads();
  if (t < 45) {
    float acc = 0.f;
    for (int j = 0; j < 130; ++j) acc += p[j] * qkv[(size_t)j * 135 + 90 + t];
    ao[t] = acc;
  }
  __syncthreads();
  if (t < 45) {
    float pr = proj_b[t];
    #pragma unroll 5
    for (int e2 = 0; e2 < 45; ++e2) pr += ao[e2] * proj_w[e2 * 45 + t];
    ctx[(size_t)i * 45 + t] = pr;
  }
}

// ---------------- head MLP ----------------

__global__ void bias_init_kernel(const float* __restrict__ b, float* __restrict__ out, int n) {
  int i = blockIdx.x * 256 + threadIdx.x;
  if (i < n) out[i] = b[i];
}

template<bool RELU_IN>
__global__ void fc_splitk_kernel(const float* __restrict__ x, const float* __restrict__ W,
                                 float* __restrict__ out, int nin, int nout, int kchunk) {
  __shared__ float xs[128];
  int k0 = blockIdx.y * kchunk;
  int k1 = k0 + kchunk; if (k1 > nin) k1 = nin;
  int len = k1 - k0;
  for (int i = threadIdx.x; i < len; i += blockDim.x) {
    float v = x[k0 + i];
    xs[i] = RELU_IN ? fmaxf(v, 0.f) : v;
  }
  __syncthreads();
  int j = blockIdx.x * blockDim.x + threadIdx.x;
  if (j < nout) {
    float acc = 0.f;
    const float* Wp = W + (size_t)k0 * nout + j;
    for (int i = 0; i < len; ++i) acc += xs[i] * Wp[(size_t)i * nout];
    atomicAdd(&out[j], acc);
  }
}

__global__ void final_fc_kernel(const float* __restrict__ x, const float* __restrict__ W,
                                const float* __restrict__ b, float* __restrict__ out) {
  __shared__ float red[512];
  int t = threadIdx.x;
  float acc = 0.f;
  if (t < 500) acc = fmaxf(x[t], 0.f) * W[t];
  red[t] = acc;
  __syncthreads();
  #pragma unroll
  for (int off = 256; off > 0; off >>= 1) {
    if (t < off) red[t] += red[t + off];
    __syncthreads();
  }
  if (t == 0) {
    float z = red[0] + b[0];
    out[0] = 1.f / (1.f + expf(-z));
  }
}

// ---------------- host-side orchestration ----------------

struct Bufs {
  __half* slabs;         // protein: 5 slabs of n*80 halves
  __half *ligA, *ligB;   // ligand ping/pong
  float *X, *Y, *nrm, *Wp;
  int *cnt, *cur, *rp, *col, *bsum, *gcur;
  uint2* ebuf;           // aliases slabs (only live during build_csr)
};

template<int DIN, int DOUT, bool LAST>
void run_layer_prot(const Bufs& g, const float* W, const float* b, int n, hipStream_t st) {
  constexpr int PD = (DIN + 15) & ~15;
  constexpr int NPASS = PD / 16;
  int nbn = (n + 15) / 16;
  size_t slabh = (size_t)n * 80;
  for (int k = 1; k <= 4; ++k)
    gather_all_kernel<<<NPASS * nbn, 256, 0, st>>>(g.slabs + (size_t)(k - 1) * slabh,
                                                   g.rp, g.col, g.nrm,
                                                   g.slabs + (size_t)k * slabh, n, nbn);
  int wtotal = 5 * PD * DOUT;
  padw_kernel<<<(wtotal + 255) / 256, 256, 0, st>>>(W, g.Wp, DIN, DOUT, PD);
  combine_kernel<DIN, DOUT, LAST><<<(n + 63) / 64, 256, 0, st>>>(
      g.slabs, g.nrm, g.Wp, b, g.slabs, g.X, n);
}

template<int DIN, int GS, int DOUT>
void run_layer_lig(const float* xin, const Bufs& g, const float* W, const float* b,
                   int n, hipStream_t st) {
  int nb = (n + 3) / 4;
  init_gemm_kernel<DIN, GS, DOUT><<<nb, 256, 0, st>>>(xin, g.nrm, W, b, g.ligA, g.Y, n);
  const __half* gin = g.ligA;
  __half* gout = g.ligB;
  for (int k = 1; k <= 4; ++k) {
    if (k < 4)
      fused_hop_kernel<DIN, GS, DOUT, true, false><<<nb, 256, 0, st>>>(gin, g.rp, g.col, g.nrm, W, gout, g.Y, g.X, k, n);
    else
      fused_hop_kernel<DIN, GS, DOUT, false, true><<<nb, 256, 0, st>>>(gin, g.rp, g.col, g.nrm, W, gout, g.Y, g.X, 4, n);
    __half* t = (__half*)gin; gin = gout; gout = t;
  }
}

void build_csr(const int* src, const int* dst, const Bufs& g, int n, int e, hipStream_t st) {
  hipMemsetAsync(g.cnt, 0, (size_t)n * 4, st);
  hipMemsetAsync(g.cur, 0, (size_t)n * 4, st);
  hist_kernel<<<(e + 255) / 256, 256, 0, st>>>(dst, g.cnt, e);
  int nb1 = (n + 1023) / 1024;
  scan1_kernel<<<nb1, 256, 0, st>>>(g.cnt, g.rp, g.bsum, g.nrm, n);
  scan2_kernel<<<1, 256, 0, st>>>(g.bsum, nb1, g.rp + n);
  scan3_kernel<<<(n + 255) / 256, 256, 0, st>>>(g.rp, g.bsum, n);
  // bucketed two-pass scatter (col writes stay in L2-resident windows)
  gcur_init_kernel<<<1, 64, 0, st>>>(g.rp, g.gcur, n);
  scat1_kernel<<<(e + 4095) / 4096, 256, 0, st>>>(src, dst, g.gcur, g.ebuf, e);
  scat2_kernel<<<(e + 255) / 256, 256, 0, st>>>(g.ebuf, g.rp, g.cur, g.col, e);
}

} // namespace

extern "C" void kernel_launch(void* const* d_in, const int* in_sizes, int n_in,
                              void* d_out, int out_size, void* d_ws, size_t ws_size,
                              hipStream_t stream) {
  (void)in_sizes; (void)n_in; (void)out_size;

  const float* prot_x = (const float*)d_in[0];
  const float* lig_x  = (const float*)d_in[1];
  const float* pW[3] = {(const float*)d_in[2], (const float*)d_in[4], (const float*)d_in[6]};
  const float* pB[3] = {(const float*)d_in[3], (const float*)d_in[5], (const float*)d_in[7]};
  const float* lW[4] = {(const float*)d_in[8], (const float*)d_in[10], (const float*)d_in[12], (const float*)d_in[14]};
  const float* lB[4] = {(const float*)d_in[9], (const float*)d_in[11], (const float*)d_in[13], (const float*)d_in[15]};
  const float* qkv_w = (const float*)d_in[16];
  const float* qkv_b = (const float*)d_in[17];
  const float* proj_w = (const float*)d_in[18];
  const float* proj_b = (const float*)d_in[19];
  const float* h0_w = (const float*)d_in[20];
  const float* h0_b = (const float*)d_in[21];
  const float* h1_w = (const float*)d_in[22];
  const float* h1_b = (const float*)d_in[23];
  const float* h2_w = (const float*)d_in[24];
  const float* h2_b = (const float*)d_in[25];
  const float* fc_w = (const float*)d_in[26];
  const float* fc_b = (const float*)d_in[27];
  const int* prot_src = (const int*)d_in[28];
  const int* prot_dst = (const int*)d_in[29];
  const int* prot_gid = (const int*)d_in[30];
  const int* lig_src  = (const int*)d_in[31];
  const int* lig_dst  = (const int*)d_in[32];
  const int* lig_gid  = (const int*)d_in[33];

  // workspace carve-up
  char* w = (char*)d_ws;
  size_t off = 0;
  auto alloc = [&](size_t bytes) -> void* {
    void* p = w + off;
    off += (bytes + 255) & ~(size_t)255;
    return p;
  };
  __half* slabs = (__half*)alloc((size_t)5 * NPROT * 80 * 2);   // 80 MB: g0..g4
  __half* ligA  = (__half*)alloc((size_t)NLIG * 96 * 2);
  __half* ligB  = (__half*)alloc((size_t)NLIG * 96 * 2);
  float* X   = (float*)alloc((size_t)NPROT * 45 * 4);
  float* Y   = (float*)alloc((size_t)NLIG * 50 * 4);
  float* nrm = (float*)alloc((size_t)NPROT * 4);
  float* Wp  = (float*)alloc((size_t)5 * 80 * 50 * 4 + 256);  // + scalar-OOB pad
  int* cnt   = (int*)alloc((size_t)NPROT * 4);
  int* cur   = (int*)alloc((size_t)NPROT * 4);
  int* rp    = (int*)alloc(((size_t)NPROT + 1) * 4);
  int* colb  = (int*)alloc((size_t)EPROT * 4);
  int* bsum  = (int*)alloc((size_t)256 * 4);
  int* gcur  = (int*)alloc((size_t)64 * 4);
  float* rep = (float*)alloc((size_t)65 * 45 * 4);
  float* qkvb = (float*)alloc((size_t)130 * 135 * 4);
  float* ctx  = (float*)alloc((size_t)5850 * 4);
  float* hb0  = (float*)alloc((size_t)2000 * 4);
  float* hb1  = (float*)alloc((size_t)1000 * 4);
  float* hb2  = (float*)alloc((size_t)500 * 4);
  if (off > ws_size) return;  // workspace too small: fail loudly via validation

  hipMemsetAsync(rep, 0, (size_t)65 * 45 * 4, stream);

  Bufs g{slabs, ligA, ligB, X, Y, nrm, Wp, cnt, cur, rp, colb, bsum, gcur,
         (uint2*)slabs /*ebuf aliases slabs*/};

  // ---- protein GNN (chunked L2-resident gathers + wave-split combine) ----
  build_csr(prot_src, prot_dst, g, NPROT, EPROT, stream);   // ebuf uses slabs (dead here)
  init_g0_kernel<74><<<(NPROT + 3) / 4, 256, 0, stream>>>(prot_x, g.nrm, g.slabs, NPROT);
  run_layer_prot<74, 50, false>(g, pW[0], pB[0], NPROT, stream);
  run_layer_prot<50, 45, false>(g, pW[1], pB[1], NPROT, stream);
  run_layer_prot<45, 45, true >(g, pW[2], pB[2], NPROT, stream);
  segmax_kernel<<<(NPROT + 255) / 256, 256, 0, stream>>>(g.X, prot_gid, rep, NPROT, 1);

  // ---- ligand GNN (small; fused path; slabs dead again -> ebuf reuse ok) ----
  build_csr(lig_src, lig_dst, g, NLIG, ELIG, stream);
  run_layer_lig<74, 96, 50>(lig_x, g, lW[0], lB[0], NLIG, stream);
  run_layer_lig<50, 64, 45>(g.X, g, lW[1], lB[1], NLIG, stream);
  run_layer_lig<45, 64, 45>(g.X, g, lW[2], lB[2], NLIG, stream);
  run_layer_lig<45, 64, 45>(g.X, g, lW[3], lB[3], NLIG, stream);
  segmax_kernel<<<(NLIG + 255) / 256, 256, 0, stream>>>(g.X, lig_gid, rep, NLIG, 0);

  // ---- attention ----
  qkv_kernel<<<130, 256, 0, stream>>>(rep, qkv_w, qkv_b, qkvb);
  attn_kernel<<<130, 256, 0, stream>>>(qkvb, proj_w, proj_b, ctx);

  // ---- head MLP (split-K blown up for occupancy: 512/128/32 blocks) ----
  bias_init_kernel<<<8, 256, 0, stream>>>(h0_b, hb0, 2000);
  fc_splitk_kernel<false><<<dim3(8, 64), 256, 0, stream>>>(ctx, h0_w, hb0, 5850, 2000, 92);
  bias_init_kernel<<<4, 256, 0, stream>>>(h1_b, hb1, 1000);
  fc_splitk_kernel<true><<<dim3(4, 32), 256, 0, stream>>>(hb0, h1_w, hb1, 2000, 1000, 63);
  bias_init_kernel<<<2, 256, 0, stream>>>(h2_b, hb2, 500);
  fc_splitk_kernel<true><<<dim3(2, 16), 256, 0, stream>>>(hb1, h2_w, hb2, 1000, 500, 63);
  final_fc_kernel<<<1, 512, 0, stream>>>(hb2, fc_w, fc_b, (float*)d_out);
}

// Round 14
// 1243.150 us; speedup vs baseline: 1.7181x; 1.0486x over previous
//
#include <hip/hip_runtime.h>
#include <hip/hip_fp16.h>
#include <cstddef>
#include <cstdint>

namespace {

typedef _Float16 h2v __attribute__((ext_vector_type(2)));

constexpr int NPROT = 100000;
constexpr int EPROT = 1600000;
constexpr int NLIG  = 5000;
constexpr int ELIG  = 80000;

// ---------------- CSR construction ----------------

__global__ void hist_kernel(const int* __restrict__ dst, int* __restrict__ cnt, int e) {
  int i = blockIdx.x * 256 + threadIdx.x;
  if (i < e) atomicAdd(&cnt[dst[i]], 1);
}

// per-block (1024 elems) exclusive scan; also computes nrm = max(deg,1)^-0.5
__global__ void scan1_kernel(const int* __restrict__ cnt, int* __restrict__ rp,
                             int* __restrict__ bsum, float* __restrict__ nrm, int n) {
  __shared__ int wsum[4];
  int t = threadIdx.x;
  int base = blockIdx.x * 1024 + t * 4;
  int v0 = 0, v1 = 0, v2 = 0, v3 = 0;
  if (base + 3 < n) {
    int4 val = *(const int4*)(cnt + base);
    v0 = val.x; v1 = val.y; v2 = val.z; v3 = val.w;
  } else if (base < n) {
    v0 = cnt[base];
    if (base + 1 < n) v1 = cnt[base + 1];
    if (base + 2 < n) v2 = cnt[base + 2];
  }
  if (base < n)     nrm[base]     = 1.0f / sqrtf(fmaxf((float)v0, 1.0f));
  if (base + 1 < n) nrm[base + 1] = 1.0f / sqrtf(fmaxf((float)v1, 1.0f));
  if (base + 2 < n) nrm[base + 2] = 1.0f / sqrtf(fmaxf((float)v2, 1.0f));
  if (base + 3 < n) nrm[base + 3] = 1.0f / sqrtf(fmaxf((float)v3, 1.0f));
  int ts = v0 + v1 + v2 + v3;
  int lane = t & 63, wv = t >> 6;
  int incl = ts;
  #pragma unroll
  for (int off = 1; off < 64; off <<= 1) {
    int o = __shfl_up(incl, off, 64);
    if (lane >= off) incl += o;
  }
  if (lane == 63) wsum[wv] = incl;
  __syncthreads();
  int woff = 0;
  #pragma unroll
  for (int i = 0; i < 4; ++i) if (i < wv) woff += wsum[i];
  int excl = woff + incl - ts;
  int o0 = excl, o1 = o0 + v0, o2 = o1 + v1, o3 = o2 + v2;
  if (base + 3 < n) {
    *(int4*)(rp + base) = make_int4(o0, o1, o2, o3);
  } else if (base < n) {
    rp[base] = o0;
    if (base + 1 < n) rp[base + 1] = o1;
    if (base + 2 < n) rp[base + 2] = o2;
  }
  if (t == 255) bsum[blockIdx.x] = woff + incl;  // block total
}

// exclusive scan of <=256 block sums; writes grand total to rp[n]
__global__ void scan2_kernel(int* __restrict__ bsum, int nb, int* __restrict__ rp_end) {
  __shared__ int s[256];
  int t = threadIdx.x;
  int v = (t < nb) ? bsum[t] : 0;
  s[t] = v;
  __syncthreads();
  int val = v;
  for (int off = 1; off < 256; off <<= 1) {
    int add = (t >= off) ? s[t - off] : 0;
    __syncthreads();
    val += add;
    s[t] = val;
    __syncthreads();
  }
  if (t < nb) bsum[t] = val - v;  // exclusive
  if (t == 255) *rp_end = val;    // total
}

__global__ void scan3_kernel(int* __restrict__ rp, const int* __restrict__ bsum, int n) {
  int i = blockIdx.x * 256 + threadIdx.x;
  if (i < n) rp[i] += bsum[i >> 10];
}

// ---- bucketed two-pass edge scatter (bucket = dst>>11, col window L2-resident)

__global__ void gcur_init_kernel(const int* __restrict__ rp, int* __restrict__ gcur, int n) {
  int t = threadIdx.x;  // 1 block, 64 threads
  if (t < 64) gcur[t] = rp[min(t << 11, n)];
}

__global__ void scat1_kernel(const int* __restrict__ src, const int* __restrict__ dst,
                             int* __restrict__ gcur, uint2* __restrict__ ebuf, int e) {
  __shared__ int lh[64], lb[64];
  int t = threadIdx.x;
  if (t < 64) lh[t] = 0;
  __syncthreads();
  int base = blockIdx.x * 4096;
  int d[16], rk[16];
  #pragma unroll
  for (int j = 0; j < 16; ++j) {
    int i = base + j * 256 + t;
    if (i < e) {
      d[j] = dst[i];
      rk[j] = atomicAdd(&lh[min(d[j] >> 11, 63)], 1);
    }
  }
  __syncthreads();
  if (t < 64 && lh[t] > 0) lb[t] = atomicAdd(&gcur[t], lh[t]);
  __syncthreads();
  #pragma unroll
  for (int j = 0; j < 16; ++j) {
    int i = base + j * 256 + t;
    if (i < e)
      ebuf[lb[min(d[j] >> 11, 63)] + rk[j]] = make_uint2((unsigned)src[i], (unsigned)d[j]);
  }
}

__global__ void scat2_kernel(const uint2* __restrict__ ebuf, const int* __restrict__ rp,
                             int* __restrict__ cur, int* __restrict__ col, int e) {
  int i = blockIdx.x * 256 + threadIdx.x;
  if (i < e) {
    uint2 p = ebuf[i];
    int d = (int)p.y;
    int q = rp[d] + atomicAdd(&cur[d], 1);
    col[q] = (int)p.x;
  }
}

// ---------------- protein GNN ----------------
// g_k = nrm.*h_k stored fp16 in 16-feat chunks, padded width PD=ceil(DIN/16)*16
// (pads stay zero). Slab k (hop k) at gbase + k*slabh, slabh = n*80 halves.
// Chunk c, node v, slot s: addr = (c*n + v)*16 + s  (32B rows, L2-friendly).
// gathers: g_k = nrm^2 * sum_{src} g_{k-1}[src], one L2-resident chunk/pass.
// combine: block = 64 nodes; 4 waves each own a wave-uniform quarter of DOUT;
// W pre-packed transposed fp16 pairs (Wt[j][k/2]) read via scalar loads and
// contracted with v_dot2_f32_f16 (2 MACs/instr, no cvt). Cross-wave l2norm
// via LDS; writes next g0 in-place into slab 0.

__device__ __forceinline__ float2 cvt_h2(uint32_t u) {
  __half2 h = *reinterpret_cast<__half2*>(&u);
  return make_float2(__low2float(h), __high2float(h));
}

__device__ __forceinline__ h2v bit_h2v(uint32_t u) {
  h2v r;
  *reinterpret_cast<uint32_t*>(&r) = u;
  return r;
}

// grid = NPASS*nbn (pass-major); 256 thr = 4 waves; wave = 4 nodes x 16 lanes
// (4 edge slots x 4 f4-lanes, 8B loads); 4 clamped branch-free loads in flight.
__global__ void gather_all_kernel(const __half* __restrict__ gin, const int* __restrict__ rp,
                                  const int* __restrict__ col, const float* __restrict__ nrm,
                                  __half* __restrict__ gout, int n, int nbn) {
  int pass = blockIdx.x / nbn;
  int bid = blockIdx.x - pass * nbn;
  int lane = threadIdx.x & 63, wv = threadIdx.x >> 6;
  int q = lane >> 4, r = lane & 15;
  int e_slot = r >> 2, f4 = r & 3;
  int v = bid * 16 + wv * 4 + q;
  bool vok = (v < n);
  int beg = 0, deg = 0;
  if (vok) { beg = rp[v]; deg = rp[v + 1] - beg; }
  const __half* gc = gin + (size_t)pass * n * 16;
  __half* go = gout + (size_t)pass * n * 16;
  float a0 = 0.f, a1 = 0.f, a2 = 0.f, a3 = 0.f;
  for (int base = 0; __any(base < deg); base += 16) {
    int ec = (base + r < deg) ? col[beg + base + r] : -1;
    #pragma unroll
    for (int js = 0; js < 16; js += 4) {
      int sl = (q << 4) + js + e_slot;
      int s0 = __shfl(ec, sl, 64);
      int idx = (s0 >= 0) ? s0 : 0;             // clamped: row 0 when invalid
      float m = (s0 >= 0) ? 1.f : 0.f;
      uint2 u = *(const uint2*)(gc + (size_t)idx * 16 + (f4 << 2));
      float2 p0 = cvt_h2(u.x), p1 = cvt_h2(u.y);
      a0 = fmaf(m, p0.x, a0); a1 = fmaf(m, p0.y, a1);
      a2 = fmaf(m, p1.x, a2); a3 = fmaf(m, p1.y, a3);
    }
  }
  a0 += __shfl_xor(a0, 4, 64);  a1 += __shfl_xor(a1, 4, 64);
  a2 += __shfl_xor(a2, 4, 64);  a3 += __shfl_xor(a3, 4, 64);
  a0 += __shfl_xor(a0, 8, 64);  a1 += __shfl_xor(a1, 8, 64);
  a2 += __shfl_xor(a2, 8, 64);  a3 += __shfl_xor(a3, 8, 64);
  if (vok && e_slot == 0) {
    float nm = nrm[v];
    float nm2 = nm * nm;
    __half2 w0 = __floats2half2_rn(a0 * nm2, a1 * nm2);
    __half2 w1 = __floats2half2_rn(a2 * nm2, a3 * nm2);
    uint2 st;
    st.x = *reinterpret_cast<uint32_t*>(&w0);
    st.y = *reinterpret_cast<uint32_t*>(&w1);
    *(uint2*)(go + ((size_t)v << 4) + (f4 << 2)) = st;
  }
}

// layer-1 only: g0 = x * nrm (chunked, pads zero)
template<int DIN>
__global__ void init_g0_kernel(const float* __restrict__ x, const float* __restrict__ nrm,
                               __half* __restrict__ g0, int n) {
  constexpr int PD = (DIN + 15) & ~15;
  int lane = threadIdx.x & 63;
  int v = blockIdx.x * 4 + (threadIdx.x >> 6);
  if (v >= n) return;
  float nm = nrm[v];
  for (int f = lane; f < PD; f += 64) {
    float val = (f < DIN) ? x[(size_t)v * DIN + f] * nm : 0.f;
    g0[(((size_t)(f >> 4) * n + v) << 4) + (f & 15)] = __float2half(val);
  }
}

// repack W [5*DIN][DOUT] fp32 -> Wt [DOUT][5*PD/2] packed fp16 pairs (pads 0)
__global__ void padw2_kernel(const float* __restrict__ W, uint32_t* __restrict__ Wt,
                             int din, int dout, int pd) {
  int kp2 = 5 * pd / 2;
  int total = dout * kp2;
  int i = blockIdx.x * 256 + threadIdx.x;
  if (i >= total) return;
  int j = i / kp2, k2 = i - j * kp2;
  int f0 = k2 * 2, f1 = f0 + 1;
  int hop0 = f0 / pd, rem0 = f0 - hop0 * pd;
  int hop1 = f1 / pd, rem1 = f1 - hop1 * pd;
  float a = (rem0 < din) ? W[(size_t)(hop0 * din + rem0) * dout + j] : 0.f;
  float b = (rem1 < din) ? W[(size_t)(hop1 * din + rem1) * dout + j] : 0.f;
  __half2 h = __floats2half2_rn(a, b);
  Wt[i] = *reinterpret_cast<uint32_t*>(&h);
}

// combine v6: block = 64 nodes, wave wv owns outputs [wv*QO,...) (wave-uniform
// -> Wt scalar loads); k-pairs contracted with v_dot2_f32_f16.
template<int DIN, int DOUT, bool LAST>
__global__ __launch_bounds__(256) void combine_kernel(
    const __half* __restrict__ gbase, const float* __restrict__ nrm,
    const uint32_t* __restrict__ Wt, const float* __restrict__ bias,
    __half* __restrict__ gnext, float* __restrict__ Xout, int n) {
  constexpr int PD  = (DIN + 15) & ~15;
  constexpr int NCH = PD / 16;
  constexpr int KP2 = 5 * PD / 2;
  constexpr int PDN = (DOUT + 15) & ~15;
  constexpr int QO  = ((DOUT + 7) / 8) * 2;   // even, 4*QO >= DOUT
  __shared__ float ssq[4 * 64];
  int lane = threadIdx.x & 63, wv = threadIdx.x >> 6;
  int v = blockIdx.x * 64 + lane;
  bool vok = (v < n);
  int vc = vok ? v : 0;
  const size_t slabh = (size_t)n * 80;
  int cofs = __builtin_amdgcn_readfirstlane(wv) * QO;   // wave-uniform
  float acc[QO];
  #pragma unroll
  for (int jj = 0; jj < QO; ++jj) acc[jj] = 0.f;
  for (int hop = 0; hop < 5; ++hop) {
    const __half* hrow = gbase + (size_t)hop * slabh + ((size_t)vc << 4);
    #pragma unroll 1
    for (int ch = 0; ch < NCH; ++ch) {
      uint4 u0 = *(const uint4*)hrow;
      uint4 u1 = *(const uint4*)(hrow + 8);
      uint32_t hp[8] = {u0.x, u0.y, u0.z, u0.w, u1.x, u1.y, u1.z, u1.w};
      int kb = hop * (PD / 2) + ch * 8;
      #pragma unroll
      for (int p = 0; p < 8; ++p) {
        h2v hv = bit_h2v(hp[p]);
        #pragma unroll
        for (int jj = 0; jj < QO; ++jj) {
          h2v wv2 = bit_h2v(Wt[(size_t)(cofs + jj) * KP2 + kb + p]);
          acc[jj] = __builtin_amdgcn_fdot2(hv, wv2, acc[jj], false);
        }
      }
      hrow += ((size_t)n << 4);
    }
  }
  float rn = 1.f / nrm[vc];
  float ss = 0.f;
  #pragma unroll
  for (int jj = 0; jj < QO; ++jj) {
    int j = cofs + jj;
    float y = (j < DOUT) ? fmaxf(bias[j] + acc[jj] * rn, 0.f) : 0.f;
    acc[jj] = y;
    ss += y * y;
  }
  ssq[wv * 64 + lane] = ss;
  __syncthreads();          // also orders all slab-0 reads before in-place writes
  if (!vok) return;
  float tot = ssq[lane] + ssq[64 + lane] + ssq[128 + lane] + ssq[192 + lane];
  float sc = 1.f / fmaxf(sqrtf(tot), 1e-12f);
  if (LAST) {
    #pragma unroll
    for (int jj = 0; jj < QO; ++jj) {
      int j = cofs + jj;
      if (j < DOUT) Xout[(size_t)v * DOUT + j] = acc[jj] * sc;
    }
  } else {
    float nm = nrm[v];
    #pragma unroll
    for (int jj = 0; jj < QO; jj += 2) {
      int j0 = cofs + jj;
      float a = (j0 < DOUT) ? acc[jj] * sc * nm : 0.f;
      float b = (j0 + 1 < DOUT) ? acc[jj + 1] * sc * nm : 0.f;
      int ch = j0 >> 4, s = j0 & 15;
      *(__half2*)(gnext + (((size_t)ch * n + v) << 4) + s) = __floats2half2_rn(a, b);
    }
    if (wv == 3) {
      #pragma unroll
      for (int j0 = 4 * QO; j0 < PDN; j0 += 2) {    // zero-fill padded tail
        int ch = j0 >> 4, s = j0 & 15;
        *(__half2*)(gnext + (((size_t)ch * n + v) << 4) + s) = __floats2half2_rn(0.f, 0.f);
      }
    }
  }
}

// ---------------- ligand GNN: small-n fused hop (g is L2-resident) --------

template<int DIN, int GS, int DOUT>
__global__ void init_gemm_kernel(const float* __restrict__ x, const float* __restrict__ nrm,
                                 const float* __restrict__ W, const float* __restrict__ bias,
                                 __half* __restrict__ gout, float* __restrict__ y, int n) {
  int lane = threadIdx.x & 63;
  int v = blockIdx.x * 4 + (threadIdx.x >> 6);
  if (v >= n) return;
  float nm = nrm[v];
  const float* xr = x + (size_t)v * DIN;
  float hA = (lane < DIN) ? xr[lane] : 0.f;
  float hB = 0.f;
  if constexpr (DIN > 64) { if (lane + 64 < DIN) hB = xr[lane + 64]; }
  __half* go = gout + (size_t)v * GS;
  if (lane < DIN) go[lane] = __float2half(hA * nm);
  if constexpr (DIN > 64) { if (lane + 64 < DIN) go[lane + 64] = __float2half(hB * nm); }
  int cl = (lane < DOUT) ? lane : 0;
  float acc = bias[cl];
  const float* Wk = W + cl;
  #pragma unroll
  for (int f = 0; f < DIN; ++f) {
    float hf = (f < 64) ? __shfl(hA, f, 64) : __shfl(hB, f - 64, 64);
    acc += hf * Wk[(size_t)f * DOUT];
  }
  if (lane < DOUT) y[(size_t)v * DOUT + lane] = acc;
}

template<int DIN, int GS, int DOUT, bool WRITEG, bool FINAL>
__global__ void fused_hop_kernel(const __half* __restrict__ gin, const int* __restrict__ rp,
                                 const int* __restrict__ col, const float* __restrict__ nrm,
                                 const float* __restrict__ W, __half* __restrict__ gout,
                                 float* __restrict__ y, float* __restrict__ Xout,
                                 int k, int n) {
  int lane = threadIdx.x & 63;
  int v = blockIdx.x * 4 + (threadIdx.x >> 6);
  if (v >= n) return;
  int beg = rp[v], end = rp[v + 1];
  float a0 = 0.f, a1 = 0.f;
  for (int base = beg; base < end; base += 64) {
    int m = end - base; if (m > 64) m = 64;
    int myc = (lane < m) ? col[base + lane] : 0;
    int j = 0;
    for (; j + 8 <= m; j += 8) {
      int ss[8];
      float t0[8], t1[8];
      #pragma unroll
      for (int u = 0; u < 8; ++u) ss[u] = __shfl(myc, j + u, 64);
      #pragma unroll
      for (int u = 0; u < 8; ++u) {
        const __half* rr = gin + (size_t)ss[u] * GS;
        t0[u] = (lane < DIN) ? __half2float(rr[lane]) : 0.f;
        if constexpr (DIN > 64) t1[u] = (lane + 64 < DIN) ? __half2float(rr[lane + 64]) : 0.f;
      }
      #pragma unroll
      for (int u = 0; u < 8; ++u) {
        a0 += t0[u];
        if constexpr (DIN > 64) a1 += t1[u];
      }
    }
    for (; j < m; ++j) {
      int s = __shfl(myc, j, 64);
      const __half* rr = gin + (size_t)s * GS;
      if (lane < DIN) a0 += __half2float(rr[lane]);
      if constexpr (DIN > 64) { if (lane + 64 < DIN) a1 += __half2float(rr[lane + 64]); }
    }
  }
  float nm = nrm[v];
  float hA = a0 * nm, hB = a1 * nm;
  if (WRITEG) {
    __half* go = gout + (size_t)v * GS;
    if (lane < DIN) go[lane] = __float2half(hA * nm);
    if constexpr (DIN > 64) { if (lane + 64 < DIN) go[lane + 64] = __float2half(hB * nm); }
  }
  int cl = (lane < DOUT) ? lane : 0;
  float acc = 0.f;
  if (lane < DOUT) acc = y[(size_t)v * DOUT + lane];
  const float* Wk = W + (size_t)k * DIN * DOUT + cl;
  #pragma unroll
  for (int f = 0; f < DIN; ++f) {
    float hf = (f < 64) ? __shfl(hA, f, 64) : __shfl(hB, f - 64, 64);
    acc += hf * Wk[(size_t)f * DOUT];
  }
  if constexpr (FINAL) {
    float val = (lane < DOUT) ? fmaxf(acc, 0.f) : 0.f;
    float ss2 = val * val;
    #pragma unroll
    for (int off2 = 32; off2 > 0; off2 >>= 1) ss2 += __shfl_xor(ss2, off2, 64);
    float scale = 1.f / fmaxf(sqrtf(ss2), 1e-12f);
    if (lane < DOUT) Xout[(size_t)v * DOUT + lane] = val * scale;
  } else {
    if (lane < DOUT) y[(size_t)v * DOUT + lane] = acc;
  }
}

// hierarchical segment-max (values >= 0 post relu+l2norm; rep zeroed first)
__global__ void segmax_kernel(const float* __restrict__ X, const int* __restrict__ gid,
                              float* __restrict__ rep, int n, int row_off) {
  __shared__ float tab[4][45];
  __shared__ int gids[256];
  int t = threadIdx.x;
  for (int i = t; i < 4 * 45; i += 256) ((float*)tab)[i] = 0.f;
  int v0 = blockIdx.x * 256;
  int vend = v0 + 256; if (vend > n) vend = n;
  int nv = vend - v0;
  if (t < nv) gids[t] = gid[v0 + t];
  __syncthreads();
  int g0 = gids[0];
  int total = nv * 45;
  for (int i = t; i < total; i += 256) {
    int vl = i / 45, j = i - vl * 45;
    float val = X[(size_t)(v0 + vl) * 45 + j];
    int rel = gids[vl] - g0;
    if (rel >= 0 && rel < 4)
      atomicMax((unsigned int*)&tab[rel][j], __float_as_uint(val));
    else
      atomicMax((unsigned int*)&rep[(size_t)(row_off + gids[vl]) * 45 + j], __float_as_uint(val));
  }
  __syncthreads();
  for (int i = t; i < 4 * 45; i += 256) {
    float val = ((float*)tab)[i];
    if (val > 0.f) {
      int rel = i / 45, j = i - rel * 45;
      atomicMax((unsigned int*)&rep[(size_t)(row_off + g0 + rel) * 45 + j], __float_as_uint(val));
    }
  }
}

// ---------------- attention ----------------

__global__ void qkv_kernel(const float* __restrict__ rep, const float* __restrict__ w,
                           const float* __restrict__ b, float* __restrict__ qkv) {
  int i = blockIdx.x;      // 0..129
  int t = threadIdx.x;     // 256
  __shared__ float sr[45];
  if (t < 45) sr[t] = (i < 65) ? rep[(size_t)i * 45 + t] : 0.f;
  __syncthreads();
  if (t < 135) {
    float acc = b[t];
    #pragma unroll 5
    for (int d = 0; d < 45; ++d) acc += sr[d] * w[d * 135 + t];
    qkv[(size_t)i * 135 + t] = acc;
  }
}

__global__ void attn_kernel(const float* __restrict__ qkv, const float* __restrict__ proj_w,
                            const float* __restrict__ proj_b, float* __restrict__ ctx) {
  int i = blockIdx.x;     // query row
  int t = threadIdx.x;    // 256
  __shared__ float q[45];
  __shared__ float p[130];
  __shared__ float red[256];
  __shared__ float ao[45];
  if (t < 45) q[t] = qkv[(size_t)i * 135 + t];
  __syncthreads();
  float s = -1e30f;
  if (t < 130) {
    int j = t;
    float dot = 0.f;
    #pragma unroll 5
    for (int d = 0; d < 45; ++d) dot += q[d] * qkv[(size_t)j * 135 + 45 + d];
    dot *= 0.14907119849998599f;  // 45^-0.5
    bool mz;  // mask == 0 ?
    if (i == 64 && j == 64) mz = true;
    else if (i == 64 || j == 64) mz = false;
    else mz = !(i == j && i < 65);
    s = mz ? -1e9f : dot;
  }
  red[t] = s;
  __syncthreads();
  #pragma unroll
  for (int off = 128; off > 0; off >>= 1) {
    if (t < off) red[t] = fmaxf(red[t], red[t + off]);
    __syncthreads();
  }
  float mx = red[0];
  __syncthreads();
  float e = (t < 130) ? expf(s - mx) : 0.f;
  red[t] = e;
  __syncthreads();
  #pragma unroll
  for (int off = 128; off > 0; off >>= 1) {
    if (t < off) red[t] += red[t + off];
    __syncthreads();
  }
  float denom = red[0];
  __syncthreads();
  if (t < 130) p[t] = e / denom;
  __syncthreads();
  if (t < 45) {
    float acc = 0.f;
    for (int j = 0; j < 130; ++j) acc += p[j] * qkv[(size_t)j * 135 + 90 + t];
    ao[t] = acc;
  }
  __syncthreads();
  if (t < 45) {
    float pr = proj_b[t];
    #pragma unroll 5
    for (int e2 = 0; e2 < 45; ++e2) pr += ao[e2] * proj_w[e2 * 45 + t];
    ctx[(size_t)i * 45 + t] = pr;
  }
}

// ---------------- head MLP ----------------

__global__ void bias_init_kernel(const float* __restrict__ b, float* __restrict__ out, int n) {
  int i = blockIdx.x * 256 + threadIdx.x;
  if (i < n) out[i] = b[i];
}

template<bool RELU_IN>
__global__ void fc_splitk_kernel(const float* __restrict__ x, const float* __restrict__ W,
                                 float* __restrict__ out, int nin, int nout, int kchunk) {
  __shared__ float xs[128];
  int k0 = blockIdx.y * kchunk;
  int k1 = k0 + kchunk; if (k1 > nin) k1 = nin;
  int len = k1 - k0;
  for (int i = threadIdx.x; i < len; i += blockDim.x) {
    float v = x[k0 + i];
    xs[i] = RELU_IN ? fmaxf(v, 0.f) : v;
  }
  __syncthreads();
  int j = blockIdx.x * blockDim.x + threadIdx.x;
  if (j < nout) {
    float acc = 0.f;
    const float* Wp = W + (size_t)k0 * nout + j;
    for (int i = 0; i < len; ++i) acc += xs[i] * Wp[(size_t)i * nout];
    atomicAdd(&out[j], acc);
  }
}

__global__ void final_fc_kernel(const float* __restrict__ x, const float* __restrict__ W,
                                const float* __restrict__ b, float* __restrict__ out) {
  __shared__ float red[512];
  int t = threadIdx.x;
  float acc = 0.f;
  if (t < 500) acc = fmaxf(x[t], 0.f) * W[t];
  red[t] = acc;
  __syncthreads();
  #pragma unroll
  for (int off = 256; off > 0; off >>= 1) {
    if (t < off) red[t] += red[t + off];
    __syncthreads();
  }
  if (t == 0) {
    float z = red[0] + b[0];
    out[0] = 1.f / (1.f + expf(-z));
  }
}

// ---------------- host-side orchestration ----------------

struct Bufs {
  __half* slabs;         // protein: 5 slabs of n*80 halves
  __half *ligA, *ligB;   // ligand ping/pong
  float *X, *Y, *nrm;
  uint32_t* Wt;
  int *cnt, *cur, *rp, *col, *bsum, *gcur;
  uint2* ebuf;           // aliases slabs (only live during build_csr)
};

template<int DIN, int DOUT, bool LAST>
void run_layer_prot(const Bufs& g, const float* W, const float* b, int n, hipStream_t st) {
  constexpr int PD = (DIN + 15) & ~15;
  constexpr int NPASS = PD / 16;
  int nbn = (n + 15) / 16;
  size_t slabh = (size_t)n * 80;
  for (int k = 1; k <= 4; ++k)
    gather_all_kernel<<<NPASS * nbn, 256, 0, st>>>(g.slabs + (size_t)(k - 1) * slabh,
                                                   g.rp, g.col, g.nrm,
                                                   g.slabs + (size_t)k * slabh, n, nbn);
  int wtotal = DOUT * (5 * PD / 2);
  padw2_kernel<<<(wtotal + 255) / 256, 256, 0, st>>>(W, g.Wt, DIN, DOUT, PD);
  combine_kernel<DIN, DOUT, LAST><<<(n + 63) / 64, 256, 0, st>>>(
      g.slabs, g.nrm, g.Wt, b, g.slabs, g.X, n);
}

template<int DIN, int GS, int DOUT>
void run_layer_lig(const float* xin, const Bufs& g, const float* W, const float* b,
                   int n, hipStream_t st) {
  int nb = (n + 3) / 4;
  init_gemm_kernel<DIN, GS, DOUT><<<nb, 256, 0, st>>>(xin, g.nrm, W, b, g.ligA, g.Y, n);
  const __half* gin = g.ligA;
  __half* gout = g.ligB;
  for (int k = 1; k <= 4; ++k) {
    if (k < 4)
      fused_hop_kernel<DIN, GS, DOUT, true, false><<<nb, 256, 0, st>>>(gin, g.rp, g.col, g.nrm, W, gout, g.Y, g.X, k, n);
    else
      fused_hop_kernel<DIN, GS, DOUT, false, true><<<nb, 256, 0, st>>>(gin, g.rp, g.col, g.nrm, W, gout, g.Y, g.X, 4, n);
    __half* t = (__half*)gin; gin = gout; gout = t;
  }
}

void build_csr(const int* src, const int* dst, const Bufs& g, int n, int e, hipStream_t st) {
  hipMemsetAsync(g.cnt, 0, (size_t)n * 4, st);
  hipMemsetAsync(g.cur, 0, (size_t)n * 4, st);
  hist_kernel<<<(e + 255) / 256, 256, 0, st>>>(dst, g.cnt, e);
  int nb1 = (n + 1023) / 1024;
  scan1_kernel<<<nb1, 256, 0, st>>>(g.cnt, g.rp, g.bsum, g.nrm, n);
  scan2_kernel<<<1, 256, 0, st>>>(g.bsum, nb1, g.rp + n);
  scan3_kernel<<<(n + 255) / 256, 256, 0, st>>>(g.rp, g.bsum, n);
  // bucketed two-pass scatter (col writes stay in L2-resident windows)
  gcur_init_kernel<<<1, 64, 0, st>>>(g.rp, g.gcur, n);
  scat1_kernel<<<(e + 4095) / 4096, 256, 0, st>>>(src, dst, g.gcur, g.ebuf, e);
  scat2_kernel<<<(e + 255) / 256, 256, 0, st>>>(g.ebuf, g.rp, g.cur, g.col, e);
}

} // namespace

extern "C" void kernel_launch(void* const* d_in, const int* in_sizes, int n_in,
                              void* d_out, int out_size, void* d_ws, size_t ws_size,
                              hipStream_t stream) {
  (void)in_sizes; (void)n_in; (void)out_size;

  const float* prot_x = (const float*)d_in[0];
  const float* lig_x  = (const float*)d_in[1];
  const float* pW[3] = {(const float*)d_in[2], (const float*)d_in[4], (const float*)d_in[6]};
  const float* pB[3] = {(const float*)d_in[3], (const float*)d_in[5], (const float*)d_in[7]};
  const float* lW[4] = {(const float*)d_in[8], (const float*)d_in[10], (const float*)d_in[12], (const float*)d_in[14]};
  const float* lB[4] = {(const float*)d_in[9], (const float*)d_in[11], (const float*)d_in[13], (const float*)d_in[15]};
  const float* qkv_w = (const float*)d_in[16];
  const float* qkv_b = (const float*)d_in[17];
  const float* proj_w = (const float*)d_in[18];
  const float* proj_b = (const float*)d_in[19];
  const float* h0_w = (const float*)d_in[20];
  const float* h0_b = (const float*)d_in[21];
  const float* h1_w = (const float*)d_in[22];
  const float* h1_b = (const float*)d_in[23];
  const float* h2_w = (const float*)d_in[24];
  const float* h2_b = (const float*)d_in[25];
  const float* fc_w = (const float*)d_in[26];
  const float* fc_b = (const float*)d_in[27];
  const int* prot_src = (const int*)d_in[28];
  const int* prot_dst = (const int*)d_in[29];
  const int* prot_gid = (const int*)d_in[30];
  const int* lig_src  = (const int*)d_in[31];
  const int* lig_dst  = (const int*)d_in[32];
  const int* lig_gid  = (const int*)d_in[33];

  // workspace carve-up
  char* w = (char*)d_ws;
  size_t off = 0;
  auto alloc = [&](size_t bytes) -> void* {
    void* p = w + off;
    off += (bytes + 255) & ~(size_t)255;
    return p;
  };
  __half* slabs = (__half*)alloc((size_t)5 * NPROT * 80 * 2);   // 80 MB: g0..g4
  __half* ligA  = (__half*)alloc((size_t)NLIG * 96 * 2);
  __half* ligB  = (__half*)alloc((size_t)NLIG * 96 * 2);
  float* X   = (float*)alloc((size_t)NPROT * 45 * 4);
  float* Y   = (float*)alloc((size_t)NLIG * 50 * 4);
  float* nrm = (float*)alloc((size_t)NPROT * 4);
  uint32_t* Wt = (uint32_t*)alloc((size_t)50 * 200 * 4 + 256);  // + scalar-OOB pad
  int* cnt   = (int*)alloc((size_t)NPROT * 4);
  int* cur   = (int*)alloc((size_t)NPROT * 4);
  int* rp    = (int*)alloc(((size_t)NPROT + 1) * 4);
  int* colb  = (int*)alloc((size_t)EPROT * 4);
  int* bsum  = (int*)alloc((size_t)256 * 4);
  int* gcur  = (int*)alloc((size_t)64 * 4);
  float* rep = (float*)alloc((size_t)65 * 45 * 4);
  float* qkvb = (float*)alloc((size_t)130 * 135 * 4);
  float* ctx  = (float*)alloc((size_t)5850 * 4);
  float* hb0  = (float*)alloc((size_t)2000 * 4);
  float* hb1  = (float*)alloc((size_t)1000 * 4);
  float* hb2  = (float*)alloc((size_t)500 * 4);
  if (off > ws_size) return;  // workspace too small: fail loudly via validation

  hipMemsetAsync(rep, 0, (size_t)65 * 45 * 4, stream);

  Bufs g{slabs, ligA, ligB, X, Y, nrm, Wt, cnt, cur, rp, colb, bsum, gcur,
         (uint2*)slabs /*ebuf aliases slabs*/};

  // ---- protein GNN (chunked L2-resident gathers + dot2 combine) ----
  build_csr(prot_src, prot_dst, g, NPROT, EPROT, stream);   // ebuf uses slabs (dead here)
  init_g0_kernel<74><<<(NPROT + 3) / 4, 256, 0, stream>>>(prot_x, g.nrm, g.slabs, NPROT);
  run_layer_prot<74, 50, false>(g, pW[0], pB[0], NPROT, stream);
  run_layer_prot<50, 45, false>(g, pW[1], pB[1], NPROT, stream);
  run_layer_prot<45, 45, true >(g, pW[2], pB[2], NPROT, stream);
  segmax_kernel<<<(NPROT + 255) / 256, 256, 0, stream>>>(g.X, prot_gid, rep, NPROT, 1);

  // ---- ligand GNN (small; fused path; slabs dead again -> ebuf reuse ok) ----
  build_csr(lig_src, lig_dst, g, NLIG, ELIG, stream);
  run_layer_lig<74, 96, 50>(lig_x, g, lW[0], lB[0], NLIG, stream);
  run_layer_lig<50, 64, 45>(g.X, g, lW[1], lB[1], NLIG, stream);
  run_layer_lig<45, 64, 45>(g.X, g, lW[2], lB[2], NLIG, stream);
  run_layer_lig<45, 64, 45>(g.X, g, lW[3], lB[3], NLIG, stream);
  segmax_kernel<<<(NLIG + 255) / 256, 256, 0, stream>>>(g.X, lig_gid, rep, NLIG, 0);

  // ---- attention ----
  qkv_kernel<<<130, 256, 0, stream>>>(rep, qkv_w, qkv_b, qkvb);
  attn_kernel<<<130, 256, 0, stream>>>(qkvb, proj_w, proj_b, ctx);

  // ---- head MLP (split-K blown up for occupancy: 512/128/32 blocks) ----
  bias_init_kernel<<<8, 256, 0, stream>>>(h0_b, hb0, 2000);
  fc_splitk_kernel<false><<<dim3(8, 64), 256, 0, stream>>>(ctx, h0_w, hb0, 5850, 2000, 92);
  bias_init_kernel<<<4, 256, 0, stream>>>(h1_b, hb1, 1000);
  fc_splitk_kernel<true><<<dim3(4, 32), 256, 0, stream>>>(hb0, h1_w, hb1, 2000, 1000, 63);
  bias_init_kernel<<<2, 256, 0, stream>>>(h2_b, hb2, 500);
  fc_splitk_kernel<true><<<dim3(2, 16), 256, 0, stream>>>(hb1, h2_w, hb2, 1000, 500, 63);
  final_fc_kernel<<<1, 512, 0, stream>>>(hb2, fc_w, fc_b, (float*)d_out);
}